// Round 14
// baseline (1531.508 us; speedup 1.0000x reference)
//
#include <hip/hip_runtime.h>
#include <hip/hip_bf16.h>
#include <math.h>

typedef float f32x4 __attribute__((ext_vector_type(4)));
typedef float f32x2 __attribute__((ext_vector_type(2)));
typedef short s16x8 __attribute__((ext_vector_type(8)));
typedef short s16x4 __attribute__((ext_vector_type(4)));
typedef int   i32x4 __attribute__((ext_vector_type(4)));

__device__ __forceinline__ short f2bf(float f) {
  __hip_bfloat16 h = __float2bfloat16(f);
  return __builtin_bit_cast(short, h);
}
__device__ __forceinline__ float bf2f(short s) {
  __hip_bfloat16 h = __builtin_bit_cast(__hip_bfloat16, s);
  return __bfloat162float(h);
}
__device__ __forceinline__ float gelu_f(float x) {
  return 0.5f * x * (1.f + erff(x * 0.70710678118654752440f));
}
__device__ __forceinline__ float waveSum(float v) {
  #pragma unroll
  for (int d = 32; d; d >>= 1) v += __shfl_xor(v, d);
  return v;
}

// ---------------------------------------------------------------------------
// P0: one-shot weight transpose to bf16 (attention weights).
// ---------------------------------------------------------------------------
__global__ __launch_bounds__(256) void prep_w_k(
    const float* __restrict__ qkv_w, const float* __restrict__ attn_pw,
    short* __restrict__ wTg, short* __restrict__ pwTg)
{
  int idx = blockIdx.x * 256 + threadIdx.x;
  if (idx < 24576) {                 // 1536*128/8
    int r = idx >> 4;
    int k0 = (idx & 15) * 8;
    s16x8 v;
    #pragma unroll
    for (int m = 0; m < 8; ++m) v[m] = f2bf(qkv_w[(size_t)(k0 + m) * 1536 + r]);
    *reinterpret_cast<s16x8*>(&wTg[r * 128 + k0]) = v;
  } else if (idx < 24576 + 16384) {  // 256*512/8
    int e = idx - 24576;
    int r = e >> 6;
    int k0 = (e & 63) * 8;
    s16x8 v;
    #pragma unroll
    for (int m = 0; m < 8; ++m) v[m] = f2bf(attn_pw[(size_t)(k0 + m) * 256 + r]);
    *reinterpret_cast<s16x8*>(&pwTg[r * 512 + k0]) = v;
  }
}

// ---------------------------------------------------------------------------
// P1: per-K-slice fp32->bf16 tile-pack of a big weight matrix.
// Bp[kt][Npad][64] <- Bw[kbeg + kt*64 + k][n]  (zero-padded k>=Kreal, n>=ldb)
// LDS 64x64 tile transpose: coalesced read rows, packed contiguous write.
// ---------------------------------------------------------------------------
__global__ __launch_bounds__(256) void prep_slice_k(
    const float* __restrict__ Bw, short* __restrict__ Bp,
    int ldb, int Kreal, int kbeg, int ntile64, int Npad)
{
  __shared__ float tile[64][65];
  const int nt = blockIdx.x % ntile64, kt = blockIdx.x / ntile64;
  const int t = threadIdx.x;
  #pragma unroll
  for (int i = 0; i < 16; ++i) {
    int e = i * 256 + t, r = e >> 6, c = e & 63;
    int gk = kbeg + kt * 64 + r, gn = nt * 64 + c;
    tile[r][c] = (gk < Kreal && gn < ldb) ? Bw[(size_t)gk * ldb + gn] : 0.f;
  }
  __syncthreads();
  const int c = t >> 2, q = t & 3;     // consecutive t -> contiguous 32B writes
  s16x8 v0, v1;
  #pragma unroll
  for (int m = 0; m < 8; ++m) {
    v0[m] = f2bf(tile[q*16 + m][c]);
    v1[m] = f2bf(tile[q*16 + 8 + m][c]);
  }
  short* dst = Bp + ((size_t)kt * Npad + nt * 64 + c) * 64 + q * 16;
  *reinterpret_cast<s16x8*>(dst) = v0;
  *reinterpret_cast<s16x8*>(dst + 8) = v1;
}

// ---------------------------------------------------------------------------
// G2: barrier-free, LDS-free MLP GEMM.
// Each WAVE is independent: owns output tile (rg*64 rows x nt*64 cols) for
// one K-slice. A-frags direct from tile-packed Ap (L2); B-frags direct from
// tile-packed Bp (contiguous 8KB/step stream, LLC-warm from prep).
// No __syncthreads anywhere -> nothing serializes; occupancy does the hiding.
// ---------------------------------------------------------------------------
__global__ __launch_bounds__(256, 3) void gemm_nolds_k(
    const short* __restrict__ Ap, const short* __restrict__ Bp,
    float* __restrict__ part,
    int Npad, int ktbase, int nsteps, int ntiles, int z)
{
  const int t = threadIdx.x, lane = t & 63, w = t >> 6;
  const int ln15 = lane & 15, hi = lane >> 4;
  const int W = blockIdx.x * 4 + w;
  const int nt = W % ntiles, rg = W / ntiles;
  const int m0 = rg * 64, n0 = nt * 64;

  f32x4 acc[4][4] = {};

  for (int s = 0; s < nsteps; ++s) {
    const short* at = Ap + ((size_t)(ktbase + s) * 512 + m0) * 64;
    const short* bt = Bp + ((size_t)s * Npad + n0) * 64;
    s16x8 af[8], bf[8];
    #pragma unroll
    for (int kk = 0; kk < 2; ++kk)
      #pragma unroll
      for (int f = 0; f < 4; ++f) {
        af[kk*4 + f] = *reinterpret_cast<const s16x8*>(
            &at[(f*16 + ln15) * 64 + (kk*4 + hi) * 8]);
        bf[kk*4 + f] = *reinterpret_cast<const s16x8*>(
            &bt[(f*16 + ln15) * 64 + (kk*4 + hi) * 8]);
      }
    #pragma unroll
    for (int kk = 0; kk < 2; ++kk)
      #pragma unroll
      for (int fm = 0; fm < 4; ++fm)
        #pragma unroll
        for (int fn = 0; fn < 4; ++fn)
          acc[fm][fn] = __builtin_amdgcn_mfma_f32_16x16x32_bf16(
              af[kk*4 + fm], bf[kk*4 + fn], acc[fm][fn], 0, 0, 0);
  }

  #pragma unroll
  for (int fm = 0; fm < 4; ++fm)
    #pragma unroll
    for (int fn = 0; fn < 4; ++fn)
      #pragma unroll
      for (int j = 0; j < 4; ++j)
        part[((size_t)z * 512 + m0 + fm*16 + hi*4 + j) * Npad + n0 + fn*16 + ln15]
            = acc[fm][fn][j];
}

// ---------------------------------------------------------------------------
// F1 v3: fused per-board attention branch (unchanged from R13).
// ---------------------------------------------------------------------------
__global__ __launch_bounds__(256, 2) void fused_attn_k(
    const float* __restrict__ x,
    const float* __restrict__ qln_g, const float* __restrict__ qln_b,
    const float* __restrict__ pln_g, const float* __restrict__ pln_b,
    const short* __restrict__ wTg, const float* __restrict__ qkv_b,
    const short* __restrict__ pwTg, const float* __restrict__ attn_pb,
    const float* __restrict__ aln_g, const float* __restrict__ aln_b,
    const float* __restrict__ relb, const float* __restrict__ scale_p,
    short* __restrict__ lnp, float* __restrict__ ab)
{
  __shared__ __align__(16) char arena[73216];
  short (*lnq)[136] = reinterpret_cast<short(*)[136]>(arena + 0);      // 17408
  short (*vlds)[72] = reinterpret_cast<short(*)[72]>(arena + 17408);   // 18432
  short (*avl)[136] = reinterpret_cast<short(*)[136]>(arena + 17408);  // alias
  short (*q64)[72]  = reinterpret_cast<short(*)[72]>(arena + 35840);   // 9216
  short (*k64)[72]  = reinterpret_cast<short(*)[72]>(arena + 45056);   // 9216
  short (*p64)[72]  = reinterpret_cast<short(*)[72]>(arena + 54272);   // 9216
  float* sqb  = reinterpret_cast<float*>(arena + 63488);  // 1536 f32
  float* rb   = reinterpret_cast<float*>(arena + 69632);  // 127 f32
  float* sapb = reinterpret_cast<float*>(arena + 70144);  // 256
  float* sag  = reinterpret_cast<float*>(arena + 71168);  // 256
  float* sab2 = reinterpret_cast<float*>(arena + 72192);  // 256

  const int t = threadIdx.x, lane = t & 63, w = t >> 6;
  const int ln15 = lane & 15, hi = lane >> 4;
  const int b = blockIdx.x;

  if (t < 127) rb[t] = relb[t];
  sapb[t] = attn_pb[t]; sag[t] = aln_g[t]; sab2[t] = aln_b[t];
  #pragma unroll
  for (int i = 0; i < 6; ++i) sqb[i*256 + t] = qkv_b[i*256 + t];

  {
    int c = lane * 2;
    float qg0 = qln_g[c], qg1 = qln_g[c+1], qb0 = qln_b[c], qb1 = qln_b[c+1];
    float pg0 = pln_g[c], pg1 = pln_g[c+1], pb0 = pln_b[c], pb1 = pln_b[c+1];
    for (int i = 0; i < 16; ++i) {
      int r = w * 16 + i;
      f32x2 v = *reinterpret_cast<const f32x2*>(&x[((size_t)b*64 + r)*128 + c]);
      float s = v[0] + v[1], sq = v[0]*v[0] + v[1]*v[1];
      s = waveSum(s); sq = waveSum(sq);
      float m = s * (1.f/128.f);
      float rstd = rsqrtf(sq*(1.f/128.f) - m*m + 1e-5f);
      float a0 = (v[0]-m)*rstd, a1 = (v[1]-m)*rstd;
      unsigned u0 = (unsigned short)f2bf(a0*qg0 + qb0);
      unsigned u1 = (unsigned short)f2bf(a1*qg1 + qb1);
      *reinterpret_cast<unsigned*>(&lnq[r][c]) = u0 | (u1 << 16);
      unsigned p0 = (unsigned short)f2bf(a0*pg0 + pb0);
      unsigned p1 = (unsigned short)f2bf(a1*pg1 + pb1);
      ((unsigned*)lnp)[((size_t)b*64 + r)*64 + lane] = p0 | (p1 << 16);
    }
  }
  __syncthreads();

  auto gemm4g = [&](int coff, f32x4 (&acc)[4]) {
    #pragma unroll
    for (int kk = 0; kk < 4; ++kk) {
      s16x8 af = *reinterpret_cast<const s16x8*>(&lnq[w*16 + ln15][kk*32 + hi*8]);
      #pragma unroll
      for (int fn = 0; fn < 4; ++fn) {
        int col = coff + fn*16 + ln15;
        s16x8 bf = *reinterpret_cast<const s16x8*>(&wTg[(size_t)col*128 + kk*32 + hi*8]);
        acc[fn] = __builtin_amdgcn_mfma_f32_16x16x32_bf16(af, bf, acc[fn], 0, 0, 0);
      }
    }
  };
  auto gemm8g = [&](int coff, f32x4 (&acc)[8]) {
    #pragma unroll
    for (int kk = 0; kk < 4; ++kk) {
      s16x8 af = *reinterpret_cast<const s16x8*>(&lnq[w*16 + ln15][kk*32 + hi*8]);
      #pragma unroll
      for (int fn = 0; fn < 8; ++fn) {
        int col = coff + fn*16 + ln15;
        s16x8 bf = *reinterpret_cast<const s16x8*>(&wTg[(size_t)col*128 + kk*32 + hi*8]);
        acc[fn] = __builtin_amdgcn_mfma_f32_16x16x32_bf16(af, bf, acc[fn], 0, 0, 0);
      }
    }
  };

  f32x4 sacc[4] = {};
  for (int kc = 0; kc < 8; ++kc) {
    __syncthreads();
    f32x4 qa[4] = {};
    gemm4g(kc * 64, qa);
    #pragma unroll
    for (int fn = 0; fn < 4; ++fn) {
      float bias = sqb[kc*64 + fn*16 + ln15];
      #pragma unroll
      for (int j = 0; j < 4; ++j)
        q64[w*16 + hi*4 + j][fn*16 + ln15] = f2bf(qa[fn][j] + bias);
    }
    f32x4 ka[4] = {};
    gemm4g(512 + kc * 64, ka);
    #pragma unroll
    for (int fn = 0; fn < 4; ++fn) {
      float bias = sqb[512 + kc*64 + fn*16 + ln15];
      #pragma unroll
      for (int j = 0; j < 4; ++j)
        k64[w*16 + hi*4 + j][fn*16 + ln15] = f2bf(ka[fn][j] + bias);
    }
    __syncthreads();
    #pragma unroll
    for (int kk = 0; kk < 2; ++kk) {
      s16x8 aq = *reinterpret_cast<const s16x8*>(&q64[16*w + ln15][kk*32 + hi*8]);
      #pragma unroll
      for (int fn = 0; fn < 4; ++fn) {
        s16x8 bk = *reinterpret_cast<const s16x8*>(&k64[fn*16 + ln15][kk*32 + hi*8]);
        sacc[fn] = __builtin_amdgcn_mfma_f32_16x16x32_bf16(aq, bk, sacc[fn], 0, 0, 0);
      }
    }
  }

  {
    float scale = scale_p[0];
    #pragma unroll
    for (int j = 0; j < 4; ++j) {
      int row = 16*w + hi*4 + j;
      float pv[4];
      float mx = -1e30f;
      #pragma unroll
      for (int fn = 0; fn < 4; ++fn) {
        int col = fn*16 + ln15;
        pv[fn] = sacc[fn][j] + rb[col - row + 63];
        mx = fmaxf(mx, pv[fn]);
      }
      #pragma unroll
      for (int d = 1; d < 16; d <<= 1) mx = fmaxf(mx, __shfl_xor(mx, d));
      float sum = 0.f;
      #pragma unroll
      for (int fn = 0; fn < 4; ++fn) { pv[fn] = __expf(pv[fn] - mx); sum += pv[fn]; }
      #pragma unroll
      for (int d = 1; d < 16; d <<= 1) sum += __shfl_xor(sum, d);
      float inv = scale / sum;
      #pragma unroll
      for (int fn = 0; fn < 4; ++fn) p64[row][fn*16 + ln15] = f2bf(pv[fn] * inv);
    }
  }

  f32x4 pracc[16] = {};
  for (int cc = 0; cc < 4; ++cc) {
    __syncthreads();
    f32x4 va[8] = {};
    gemm8g(1024 + cc * 128, va);
    #pragma unroll
    for (int fn = 0; fn < 8; ++fn) {
      float bias = sqb[1024 + cc*128 + fn*16 + ln15];
      s16x4 vv;
      #pragma unroll
      for (int j = 0; j < 4; ++j) vv[j] = f2bf(va[fn][j] + bias);
      *reinterpret_cast<s16x4*>(&vlds[fn*16 + ln15][w*16 + hi*4]) = vv;
    }
    __syncthreads();
    f32x4 pacc[8] = {};
    #pragma unroll
    for (int kk = 0; kk < 2; ++kk) {
      s16x8 ap = *reinterpret_cast<const s16x8*>(&p64[16*w + ln15][kk*32 + hi*8]);
      #pragma unroll
      for (int fn = 0; fn < 8; ++fn) {
        s16x8 bv = *reinterpret_cast<const s16x8*>(&vlds[fn*16 + ln15][kk*32 + hi*8]);
        pacc[fn] = __builtin_amdgcn_mfma_f32_16x16x32_bf16(ap, bv, pacc[fn], 0, 0, 0);
      }
    }
    __syncthreads();
    #pragma unroll
    for (int fn = 0; fn < 8; ++fn)
      #pragma unroll
      for (int j = 0; j < 4; ++j)
        avl[w*16 + hi*4 + j][fn*16 + ln15] = f2bf(pacc[fn][j]);
    __syncthreads();
    #pragma unroll
    for (int kk = 0; kk < 4; ++kk) {
      s16x8 aa = *reinterpret_cast<const s16x8*>(&avl[16*w + ln15][kk*32 + hi*8]);
      #pragma unroll
      for (int fn = 0; fn < 16; ++fn) {
        s16x8 pb = *reinterpret_cast<const s16x8*>(
            &pwTg[(size_t)(fn*16 + ln15)*512 + cc*128 + kk*32 + hi*8]);
        pracc[fn] = __builtin_amdgcn_mfma_f32_16x16x32_bf16(aa, pb, pracc[fn], 0, 0, 0);
      }
    }
  }

  #pragma unroll
  for (int j = 0; j < 4; ++j) {
    int row = 16*w + hi*4 + j;
    float vv[16];
    float s = 0.f, sq = 0.f;
    #pragma unroll
    for (int fn = 0; fn < 16; ++fn) {
      vv[fn] = pracc[fn][j] + sapb[fn*16 + ln15];
      s += vv[fn]; sq += vv[fn]*vv[fn];
    }
    #pragma unroll
    for (int d = 1; d < 16; d <<= 1) { s += __shfl_xor(s, d); sq += __shfl_xor(sq, d); }
    float m = s * (1.f/256.f);
    float rstd = rsqrtf(sq*(1.f/256.f) - m*m + 1e-5f);
    #pragma unroll
    for (int fn = 0; fn < 16; ++fn) {
      int col = fn*16 + ln15;
      ab[((size_t)b*64 + row)*256 + col] = (vv[fn]-m)*rstd*sag[col] + sab2[col];
    }
  }
}

// ---------------------------------------------------------------------------
// Generic bf16-MFMA GEMM for the small GEMMs (pin / pout).
// ---------------------------------------------------------------------------
template<int BM, int BN, int WM, int WN, int EPI>
__global__ __launch_bounds__(256) void gemm_k(
    const short* __restrict__ A, const float* __restrict__ Bw,
    const float* __restrict__ bias, const float* __restrict__ res,
    void* __restrict__ O0, void* __restrict__ O1,
    int M, int N, int K, int Nreal, int Kreal)
{
  constexpr int BK = 64;
  __shared__ __align__(16) short As[BM][BK + 8];
  __shared__ __align__(16) short Bs[BN][BK + 8];
  const int t = threadIdx.x;
  const int lane = t & 63;
  const int w = t >> 6;
  const int wm = w / WN, wn = w % WN;
  const int ln15 = lane & 15, hi = lane >> 4;
  const int m0 = blockIdx.y * BM;
  const int n0 = blockIdx.x * BN;

  f32x4 acc[4][4] = {};

  for (int k0 = 0; k0 < K; k0 += BK) {
    #pragma unroll
    for (int i = 0; i < (BM*BK)/(256*8); ++i) {
      int e = (i*256 + t) * 8;
      int r = e / BK, c = e % BK;
      *reinterpret_cast<i32x4*>(&As[r][c]) =
          *reinterpret_cast<const i32x4*>(&A[(size_t)(m0 + r) * K + k0 + c]);
    }
    #pragma unroll
    for (int i = 0; i < (BK*BN)/256; ++i) {
      int idx = i*256 + t;
      int n = idx % BN, k = idx / BN;
      int gk = k0 + k, gn = n0 + n;
      float v = (gk < Kreal && gn < Nreal) ? Bw[(size_t)gk * Nreal + gn] : 0.f;
      Bs[n][k] = f2bf(v);
    }
    __syncthreads();
    #pragma unroll
    for (int kk = 0; kk < BK; kk += 32) {
      s16x8 af[4], bfr[4];
      #pragma unroll
      for (int fm = 0; fm < 4; ++fm)
        af[fm] = *reinterpret_cast<const s16x8*>(&As[wm*64 + fm*16 + ln15][kk + hi*8]);
      #pragma unroll
      for (int fn = 0; fn < 4; ++fn)
        bfr[fn] = *reinterpret_cast<const s16x8*>(&Bs[wn*64 + fn*16 + ln15][kk + hi*8]);
      #pragma unroll
      for (int fm = 0; fm < 4; ++fm)
        #pragma unroll
        for (int fn = 0; fn < 4; ++fn)
          acc[fm][fn] = __builtin_amdgcn_mfma_f32_16x16x32_bf16(
              af[fm], bfr[fn], acc[fm][fn], 0, 0, 0);
    }
    __syncthreads();
  }

  #pragma unroll
  for (int fm = 0; fm < 4; ++fm) {
    #pragma unroll
    for (int fn = 0; fn < 4; ++fn) {
      #pragma unroll
      for (int j = 0; j < 4; ++j) {
        int row = m0 + wm*64 + fm*16 + hi*4 + j;
        int col = n0 + wn*64 + fn*16 + ln15;
        float v = acc[fm][fn][j];
        if constexpr (EPI == 2) {
          v = gelu_f(v + bias[col]);
          if (col < 256) ((float*)O0)[(size_t)row * 256 + col] = v;
          else ((short*)O1)[(size_t)row * 256 + (col - 256)] = f2bf(v);
        } else { // 3
          v += bias[col] + res[(size_t)row * N + col];
          ((float*)O0)[(size_t)row * N + col] = v;
        }
      }
    }
  }
}

// ---------------------------------------------------------------------------
// K3: LayerNorm over 8192 (mlp_ln) -> bf16, TILE-PACKED output
// ---------------------------------------------------------------------------
__global__ __launch_bounds__(256) void ln8192_k(
    const float* __restrict__ x1,
    const float* __restrict__ g, const float* __restrict__ bb,
    short* __restrict__ lnxp)
{
  __shared__ float red[8];
  int t = threadIdx.x, w = t >> 6, lane = t & 63;
  int b = blockIdx.x;
  const f32x4* xr = reinterpret_cast<const f32x4*>(x1 + (size_t)b * 8192);
  f32x4 vals[8];
  float s = 0.f, sq = 0.f;
  #pragma unroll
  for (int i = 0; i < 8; ++i) {
    f32x4 v = xr[t + i*256];
    vals[i] = v;
    s  += v[0]+v[1]+v[2]+v[3];
    sq += v[0]*v[0]+v[1]*v[1]+v[2]*v[2]+v[3]*v[3];
  }
  s = waveSum(s); sq = waveSum(sq);
  if (lane == 0) { red[w] = s; red[4+w] = sq; }
  __syncthreads();
  s  = red[0]+red[1]+red[2]+red[3];
  sq = red[4]+red[5]+red[6]+red[7];
  float m = s * (1.f/8192.f);
  float rstd = rsqrtf(sq * (1.f/8192.f) - m*m + 1e-5f);
  #pragma unroll
  for (int i = 0; i < 8; ++i) {
    int idx = (t + i*256) * 4;
    f32x4 g4 = reinterpret_cast<const f32x4*>(g)[t + i*256];
    f32x4 b4 = reinterpret_cast<const f32x4*>(bb)[t + i*256];
    s16x4 o;
    #pragma unroll
    for (int k = 0; k < 4; ++k) o[k] = f2bf((vals[i][k]-m)*rstd*g4[k] + b4[k]);
    size_t paddr = ((size_t)(idx >> 6) * 512 + b) * 64 + (idx & 63);
    *reinterpret_cast<s16x4*>(&lnxp[paddr]) = o;
  }
}

// ---------------------------------------------------------------------------
// split-K reduce for mlp1: h3 = gelu(sum part + b1), bf16, TILE-PACKED out
// ---------------------------------------------------------------------------
__global__ __launch_bounds__(256) void reduce_mlp1_k(
    const float* __restrict__ part, const float* __restrict__ bias,
    short* __restrict__ h3p, int N, int Nreal, int M, int ks)
{
  int col4 = (blockIdx.x * 256 + threadIdx.x) * 4;
  int row = blockIdx.y;
  if (col4 >= N) return;
  size_t base = (size_t)row * N + col4;
  size_t stride = (size_t)M * N;
  f32x4 s = *reinterpret_cast<const f32x4*>(part + base);
  for (int k = 1; k < ks; ++k)
    s += *reinterpret_cast<const f32x4*>(part + base + (size_t)k * stride);
  s16x4 o;
  #pragma unroll
  for (int j = 0; j < 4; ++j) {
    int c = col4 + j;
    float v = 0.f;
    if (c < Nreal) v = gelu_f(s[j] + bias[c]);
    o[j] = f2bf(v);
  }
  size_t paddr = ((size_t)(col4 >> 6) * 512 + row) * 64 + (col4 & 63);
  *reinterpret_cast<s16x4*>(&h3p[paddr]) = o;
}

// ---------------------------------------------------------------------------
// split-K reduce for mlp2: out = sum part + b2 + x1 (f32)
// ---------------------------------------------------------------------------
__global__ __launch_bounds__(256) void reduce_mlp2_k(
    const float* __restrict__ part, const float* __restrict__ bias,
    const float* __restrict__ x1, float* __restrict__ out, int N, int M, int ks)
{
  int col4 = (blockIdx.x * 256 + threadIdx.x) * 4;
  int row = blockIdx.y;
  size_t base = (size_t)row * N + col4;
  size_t stride = (size_t)M * N;
  f32x4 s = *reinterpret_cast<const f32x4*>(part + base);
  for (int k = 1; k < ks; ++k)
    s += *reinterpret_cast<const f32x4*>(part + base + (size_t)k * stride);
  f32x4 b4 = *reinterpret_cast<const f32x4*>(bias + col4);
  f32x4 r4 = *reinterpret_cast<const f32x4*>(x1 + base);
  #pragma unroll
  for (int j = 0; j < 4; ++j) s[j] += b4[j] + r4[j];
  *reinterpret_cast<f32x4*>(out + base) = s;
}

// ---------------------------------------------------------------------------
// K5: SGU gate (unchanged)
// ---------------------------------------------------------------------------
__global__ __launch_bounds__(256) void gate_k(
    const float* __restrict__ u, const short* __restrict__ vbf,
    const float* __restrict__ a,
    const float* __restrict__ spg_g, const float* __restrict__ spg_b,
    const float* __restrict__ spw, const float* __restrict__ spb,
    const float* __restrict__ pog, const float* __restrict__ pob,
    short* __restrict__ outn)
{
  __shared__ __align__(16) short nvb[256][72];
  __shared__ __align__(16) short spwT[64][72];
  __shared__ float s_spg[64], s_spbl[64], s_spb[64];
  __shared__ float s_pog[256], s_pob[256];
  int t = threadIdx.x, lane = t & 63, w = t >> 6;
  int ln15 = lane & 15, hi = lane >> 4;
  int b = blockIdx.x;

  if (t < 64) { s_spg[t] = spg_g[t]; s_spbl[t] = spg_b[t]; s_spb[t] = spb[t]; }
  s_pog[t] = pog[t]; s_pob[t] = pob[t];
  #pragma unroll
  for (int i = 0; i < 16; ++i) {
    int idx = i*256 + t;
    int sr = idx >> 6, tc = idx & 63;
    spwT[tc][sr] = f2bf(spw[idx]);
  }

  float vvv[64];
  {
    int c = t;
    float s = 0.f, sq = 0.f;
    #pragma unroll
    for (int si = 0; si < 64; ++si) {
      float f = bf2f(vbf[(size_t)(b*64 + si) * 256 + c]);
      vvv[si] = f; s += f; sq += f*f;
    }
    float m = s * (1.f/64.f);
    float rstd = rsqrtf(sq * (1.f/64.f) - m*m + 1e-5f);
    __syncthreads();
    #pragma unroll
    for (int si = 0; si < 64; ++si)
      nvb[c][si] = f2bf((vvv[si]-m)*rstd*s_spg[si] + s_spbl[si]);
  }
  __syncthreads();

  f32x4 yacc[4][4] = {};
  #pragma unroll
  for (int kk = 0; kk < 64; kk += 32) {
    s16x8 af[4], bfr[4];
    #pragma unroll
    for (int fm = 0; fm < 4; ++fm)
      af[fm] = *reinterpret_cast<const s16x8*>(&nvb[64*w + fm*16 + ln15][kk + hi*8]);
    #pragma unroll
    for (int fn = 0; fn < 4; ++fn)
      bfr[fn] = *reinterpret_cast<const s16x8*>(&spwT[fn*16 + ln15][kk + hi*8]);
    #pragma unroll
    for (int fm = 0; fm < 4; ++fm)
      #pragma unroll
      for (int fn = 0; fn < 4; ++fn)
        yacc[fm][fn] = __builtin_amdgcn_mfma_f32_16x16x32_bf16(
            af[fm], bfr[fn], yacc[fm][fn], 0, 0, 0);
  }
  __syncthreads();

  short (*outl)[264] = reinterpret_cast<short(*)[264]>(&nvb[0][0]);
  #pragma unroll
  for (int fm = 0; fm < 4; ++fm) {
    #pragma unroll
    for (int fn = 0; fn < 4; ++fn) {
      int crow = 64*w + fm*16 + hi*4;
      int tcol = fn*16 + ln15;
      f32x4 u4 = *reinterpret_cast<const f32x4*>(&u[(size_t)(b*64 + tcol)*256 + crow]);
      f32x4 a4 = *reinterpret_cast<const f32x4*>(&a[(size_t)(b*64 + tcol)*256 + crow]);
      #pragma unroll
      for (int j = 0; j < 4; ++j) {
        float g = gelu_f(yacc[fm][fn][j] + s_spb[tcol]);
        float o = u4[j] * (g + a4[j]);
        outl[tcol][crow + j] = f2bf(o);
      }
    }
  }
  __syncthreads();

  #pragma unroll
  for (int ri = 0; ri < 16; ++ri) {
    int trow = w*16 + ri;
    int c = lane * 4;
    s16x4 raw = *reinterpret_cast<const s16x4*>(&outl[trow][c]);
    float f0 = bf2f(raw[0]), f1 = bf2f(raw[1]), f2 = bf2f(raw[2]), f3 = bf2f(raw[3]);
    float s  = f0+f1+f2+f3;
    float sq = f0*f0+f1*f1+f2*f2+f3*f3;
    s = waveSum(s); sq = waveSum(sq);
    float m = s * (1.f/256.f);
    float rstd = rsqrtf(sq * (1.f/256.f) - m*m + 1e-5f);
    s16x4 o;
    o[0] = f2bf((f0-m)*rstd*s_pog[c+0] + s_pob[c+0]);
    o[1] = f2bf((f1-m)*rstd*s_pog[c+1] + s_pob[c+1]);
    o[2] = f2bf((f2-m)*rstd*s_pog[c+2] + s_pob[c+2]);
    o[3] = f2bf((f3-m)*rstd*s_pog[c+3] + s_pob[c+3]);
    *reinterpret_cast<s16x4*>(&outn[(size_t)(b*64 + trow)*256 + c]) = o;
  }
}

// ---------------------------------------------------------------------------
extern "C" void kernel_launch(void* const* d_in, const int* in_sizes, int n_in,
                              void* d_out, int out_size, void* d_ws, size_t ws_size,
                              hipStream_t stream)
{
  const float* x          = (const float*)d_in[0];
  const float* qkv_ln_g   = (const float*)d_in[1];
  const float* qkv_ln_b   = (const float*)d_in[2];
  const float* qkv_w      = (const float*)d_in[3];
  const float* qkv_b      = (const float*)d_in[4];
  const float* attn_pw    = (const float*)d_in[5];
  const float* attn_pb    = (const float*)d_in[6];
  const float* attn_ln_g  = (const float*)d_in[7];
  const float* attn_ln_b  = (const float*)d_in[8];
  const float* rel_bias   = (const float*)d_in[9];
  const float* scale      = (const float*)d_in[10];
  const float* pin_ln_g   = (const float*)d_in[11];
  const float* pin_ln_b   = (const float*)d_in[12];
  const float* pin_w      = (const float*)d_in[13];
  const float* pin_b      = (const float*)d_in[14];
  const float* sp_ln_g    = (const float*)d_in[15];
  const float* sp_ln_b    = (const float*)d_in[16];
  const float* sp_w       = (const float*)d_in[17];
  const float* sp_b       = (const float*)d_in[18];
  const float* pout_ln_g  = (const float*)d_in[19];
  const float* pout_ln_b  = (const float*)d_in[20];
  const float* pout_w     = (const float*)d_in[21];
  const float* pout_b     = (const float*)d_in[22];
  const float* mlp_ln_g   = (const float*)d_in[23];
  const float* mlp_ln_b   = (const float*)d_in[24];
  const float* mlp_w1     = (const float*)d_in[25];
  const float* mlp_b1     = (const float*)d_in[26];
  const float* mlp_w2     = (const float*)d_in[27];
  const float* mlp_b2     = (const float*)d_in[28];

  char* ws = (char*)d_ws;
  short* lnp   = (short*)(ws + 0);           // 8.39 MB (dead after pin gemm)
  float* x1b   = (float*)(ws + 0);           // 16.78 MB (written at pout)
  float* ab    = (float*)(ws + 16777216);    // 33.55 MB f32
  float* ub    = (float*)(ws + 50331648);    // 33.55 MB f32
  short* wTg   = (short*)(ws + 83886080);    // 393 KB (pre-pin region)
  short* pwTg  = (short*)(ws + 84279296);    // 262 KB
  short* vbfb  = (short*)(ws + 83886080);    // 16.78 MB bf16 (after fused)
  short* outnb = (short*)(ws + 100663296);   // 16.78 MB bf16 (dead after pout)
  short* lnxp  = (short*)(ws + 150994944);   // 8.39 MB (tile-packed A, mlp1)
  short* h3p   = (short*)(ws + 159383552);   // 9.31 MB (tile-packed A, mlp2)
  float* partb = (float*)(ws + 16777216);    // split-K partials (74.5 MB max;
                                             // aliases ab/ub, dead by mlp)
  short* Bpb   = (short*)(ws + 92274688);    // 37.8 MB B-slice (aliases outnb
                                             // region, dead by mlp)

  // weight transpose (once) -> wTg, pwTg
  prep_w_k<<<160, 256, 0, stream>>>(qkv_w, attn_pw, wTg, pwTg);
  // fused: LN + qkv + attention + proj + ln256  ->  lnp, ab
  fused_attn_k<<<512, 256, 0, stream>>>(
      x, qkv_ln_g, qkv_ln_b, pin_ln_g, pin_ln_b, wTg, qkv_b,
      pwTg, attn_pb, attn_ln_g, attn_ln_b, rel_bias, scale, lnp, ab);
  // pin: [32768,128]@[128,512]+b, gelu, split u (f32) / v (bf16)
  gemm_k<128,128,2,2,2><<<dim3(4,256), 256, 0, stream>>>(
      lnp, pin_w, pin_b, nullptr, ub, vbfb, 32768, 512, 128, 512, 128);
  // SGU gate + fused pout_ln -> outn bf16
  gate_k<<<512, 256, 0, stream>>>(ub, vbfb, ab, sp_ln_g, sp_ln_b, sp_w, sp_b,
                                  pout_ln_g, pout_ln_b, outnb);
  // pout: [32768,256]@[256,128]+b + x residual -> x1 f32
  gemm_k<128,128,2,2,3><<<dim3(1,256), 256, 0, stream>>>(
      outnb, pout_w, pout_b, x, x1b, nullptr, 32768, 128, 256, 128, 256);
  // LN over 8192 -> lnx (tile-packed)
  ln8192_k<<<512, 256, 0, stream>>>(x1b, mlp_ln_g, mlp_ln_b, lnxp);

  // mlp1: [512,8192] @ [8192,9011] (Npad 9088 = 142*64), 4 K-slices of 32 kt.
  // per slice: pack B-slice -> barrier-free GEMM (8*142 = 1136 indep waves).
  for (int z = 0; z < 4; ++z) {
    prep_slice_k<<<32 * 142, 256, 0, stream>>>(
        mlp_w1, Bpb, /*ldb=*/9011, /*Kreal=*/8192, /*kbeg=*/z * 2048,
        /*ntile64=*/142, /*Npad=*/9088);
    gemm_nolds_k<<<284, 256, 0, stream>>>(
        lnxp, Bpb, partb, /*Npad=*/9088, /*ktbase=*/z * 32, /*nsteps=*/32,
        /*ntiles=*/142, z);
  }
  reduce_mlp1_k<<<dim3(9, 512), 256, 0, stream>>>(partb, mlp_b1, h3p, 9088, 9011, 512, 4);

  // mlp2: [512,9088] @ [9011,8192], 4 K-slices of {36,36,36,34} kt.
  {
    const int ktb[4] = {0, 36, 72, 108};
    const int kts[4] = {36, 36, 36, 34};
    for (int z = 0; z < 4; ++z) {
      prep_slice_k<<<kts[z] * 128, 256, 0, stream>>>(
          mlp_w2, Bpb, /*ldb=*/8192, /*Kreal=*/9011, /*kbeg=*/ktb[z] * 64,
          /*ntile64=*/128, /*Npad=*/8192);
      gemm_nolds_k<<<256, 256, 0, stream>>>(
          h3p, Bpb, partb, /*Npad=*/8192, /*ktbase=*/ktb[z], /*nsteps=*/kts[z],
          /*ntiles=*/128, z);
    }
  }
  reduce_mlp2_k<<<dim3(8, 512), 256, 0, stream>>>(partb, mlp_b2, x1b, (float*)d_out, 8192, 512, 4);
}

// Round 15
// 669.013 us; speedup vs baseline: 2.2892x; 2.2892x over previous
//
#include <hip/hip_runtime.h>
#include <hip/hip_bf16.h>
#include <math.h>

typedef float f32x4 __attribute__((ext_vector_type(4)));
typedef float f32x2 __attribute__((ext_vector_type(2)));
typedef short s16x8 __attribute__((ext_vector_type(8)));
typedef short s16x4 __attribute__((ext_vector_type(4)));
typedef int   i32x4 __attribute__((ext_vector_type(4)));

__device__ __forceinline__ short f2bf(float f) {
  __hip_bfloat16 h = __float2bfloat16(f);
  return __builtin_bit_cast(short, h);
}
__device__ __forceinline__ float bf2f(short s) {
  __hip_bfloat16 h = __builtin_bit_cast(__hip_bfloat16, s);
  return __bfloat162float(h);
}
__device__ __forceinline__ float gelu_f(float x) {
  return 0.5f * x * (1.f + erff(x * 0.70710678118654752440f));
}
__device__ __forceinline__ float waveSum(float v) {
  #pragma unroll
  for (int d = 32; d; d >>= 1) v += __shfl_xor(v, d);
  return v;
}
// Soft barrier: LDS-visibility only; does NOT drain vmcnt.
__device__ __forceinline__ void softBarrier() {
  asm volatile("s_waitcnt lgkmcnt(0)" ::: "memory");
  __builtin_amdgcn_s_barrier();
  asm volatile("" ::: "memory");
}

// ---------------------------------------------------------------------------
// P0: one-shot weight transpose to bf16 (attention weights).
// ---------------------------------------------------------------------------
__global__ __launch_bounds__(256) void prep_w_k(
    const float* __restrict__ qkv_w, const float* __restrict__ attn_pw,
    short* __restrict__ wTg, short* __restrict__ pwTg)
{
  int idx = blockIdx.x * 256 + threadIdx.x;
  if (idx < 24576) {                 // 1536*128/8
    int r = idx >> 4;
    int k0 = (idx & 15) * 8;
    s16x8 v;
    #pragma unroll
    for (int m = 0; m < 8; ++m) v[m] = f2bf(qkv_w[(size_t)(k0 + m) * 1536 + r]);
    *reinterpret_cast<s16x8*>(&wTg[r * 128 + k0]) = v;
  } else if (idx < 24576 + 16384) {  // 256*512/8
    int e = idx - 24576;
    int r = e >> 6;
    int k0 = (e & 63) * 8;
    s16x8 v;
    #pragma unroll
    for (int m = 0; m < 8; ++m) v[m] = f2bf(attn_pw[(size_t)(k0 + m) * 256 + r]);
    *reinterpret_cast<s16x8*>(&pwTg[r * 512 + k0]) = v;
  }
}

// ---------------------------------------------------------------------------
// F1 v4: fused per-board attention branch.  Same math/MFMA conventions as
// R13 (verified passing).  LDS cut 73.2 -> 51.7 KB => 3 blocks/CU:
//  - p64 aliases q64 (both strictly wave-local rows; q64 reads complete
//    before p64 writes within each wave)
//  - Phase D uses 8 x 64-col chunks; vlds/avl share one 9.2 KB buffer with
//    the same barrier discipline R13 used for its 128-col alias
//  - epilogue constants read directly from global (one-time)
// ---------------------------------------------------------------------------
__global__ __launch_bounds__(256, 3) void fused_attn_k(
    const float* __restrict__ x,
    const float* __restrict__ qln_g, const float* __restrict__ qln_b,
    const float* __restrict__ pln_g, const float* __restrict__ pln_b,
    const short* __restrict__ wTg, const float* __restrict__ qkv_b,
    const short* __restrict__ pwTg, const float* __restrict__ attn_pb,
    const float* __restrict__ aln_g, const float* __restrict__ aln_b,
    const float* __restrict__ relb, const float* __restrict__ scale_p,
    short* __restrict__ lnp, float* __restrict__ ab)
{
  __shared__ __align__(16) char arena[51712];
  short (*lnq)[136] = reinterpret_cast<short(*)[136]>(arena + 0);      // 17408
  short (*vlds)[72] = reinterpret_cast<short(*)[72]>(arena + 17408);   // 9216
  short (*avl)[72]  = reinterpret_cast<short(*)[72]>(arena + 17408);   // alias
  short (*q64)[72]  = reinterpret_cast<short(*)[72]>(arena + 26624);   // 9216
  short (*p64)[72]  = reinterpret_cast<short(*)[72]>(arena + 26624);   // alias q64
  short (*k64)[72]  = reinterpret_cast<short(*)[72]>(arena + 35840);   // 9216
  float* sqb = reinterpret_cast<float*>(arena + 45056);  // 1536 f32 = 6144
  float* rb  = reinterpret_cast<float*>(arena + 51200);  // 127 f32 = 508

  const int t = threadIdx.x, lane = t & 63, w = t >> 6;
  const int ln15 = lane & 15, hi = lane >> 4;
  const int b = blockIdx.x;

  if (t < 127) rb[t] = relb[t];
  #pragma unroll
  for (int i = 0; i < 6; ++i) sqb[i*256 + t] = qkv_b[i*256 + t];

  // Phase A: row LN -> lnq (LDS bf16) and lnp (global bf16)
  {
    int c = lane * 2;
    float qg0 = qln_g[c], qg1 = qln_g[c+1], qb0 = qln_b[c], qb1 = qln_b[c+1];
    float pg0 = pln_g[c], pg1 = pln_g[c+1], pb0 = pln_b[c], pb1 = pln_b[c+1];
    for (int i = 0; i < 16; ++i) {
      int r = w * 16 + i;
      f32x2 v = *reinterpret_cast<const f32x2*>(&x[((size_t)b*64 + r)*128 + c]);
      float s = v[0] + v[1], sq = v[0]*v[0] + v[1]*v[1];
      s = waveSum(s); sq = waveSum(sq);
      float m = s * (1.f/128.f);
      float rstd = rsqrtf(sq*(1.f/128.f) - m*m + 1e-5f);
      float a0 = (v[0]-m)*rstd, a1 = (v[1]-m)*rstd;
      unsigned u0 = (unsigned short)f2bf(a0*qg0 + qb0);
      unsigned u1 = (unsigned short)f2bf(a1*qg1 + qb1);
      *reinterpret_cast<unsigned*>(&lnq[r][c]) = u0 | (u1 << 16);
      unsigned p0 = (unsigned short)f2bf(a0*pg0 + pb0);
      unsigned p1 = (unsigned short)f2bf(a1*pg1 + pb1);
      ((unsigned*)lnp)[((size_t)b*64 + r)*64 + lane] = p0 | (p1 << 16);
    }
  }
  __syncthreads();

  // out(64 x 64chunk) = lnq @ wTg[coff..] : B-frags direct from global (L2)
  auto gemm4g = [&](int coff, f32x4 (&acc)[4]) {
    #pragma unroll
    for (int kk = 0; kk < 4; ++kk) {
      s16x8 af = *reinterpret_cast<const s16x8*>(&lnq[w*16 + ln15][kk*32 + hi*8]);
      #pragma unroll
      for (int fn = 0; fn < 4; ++fn) {
        int col = coff + fn*16 + ln15;
        s16x8 bf = *reinterpret_cast<const s16x8*>(&wTg[(size_t)col*128 + kk*32 + hi*8]);
        acc[fn] = __builtin_amdgcn_mfma_f32_16x16x32_bf16(af, bf, acc[fn], 0, 0, 0);
      }
    }
  };

  // Phase B: scores = q @ k^T over 8 x 64-d chunks
  f32x4 sacc[4] = {};
  for (int kc = 0; kc < 8; ++kc) {
    __syncthreads();                   // q64/k64 overwrite vs prior QK reads
    f32x4 qa[4] = {};
    gemm4g(kc * 64, qa);
    #pragma unroll
    for (int fn = 0; fn < 4; ++fn) {
      float bias = sqb[kc*64 + fn*16 + ln15];
      #pragma unroll
      for (int j = 0; j < 4; ++j)
        q64[w*16 + hi*4 + j][fn*16 + ln15] = f2bf(qa[fn][j] + bias);
    }
    f32x4 ka[4] = {};
    gemm4g(512 + kc * 64, ka);
    #pragma unroll
    for (int fn = 0; fn < 4; ++fn) {
      float bias = sqb[512 + kc*64 + fn*16 + ln15];
      #pragma unroll
      for (int j = 0; j < 4; ++j)
        k64[w*16 + hi*4 + j][fn*16 + ln15] = f2bf(ka[fn][j] + bias);
    }
    __syncthreads();                   // q64/k64 visible
    #pragma unroll
    for (int kk = 0; kk < 2; ++kk) {
      s16x8 aq = *reinterpret_cast<const s16x8*>(&q64[16*w + ln15][kk*32 + hi*8]);
      #pragma unroll
      for (int fn = 0; fn < 4; ++fn) {
        s16x8 bk = *reinterpret_cast<const s16x8*>(&k64[fn*16 + ln15][kk*32 + hi*8]);
        sacc[fn] = __builtin_amdgcn_mfma_f32_16x16x32_bf16(aq, bk, sacc[fn], 0, 0, 0);
      }
    }
  }

  // softmax + post-softmax scale -> p64 (aliases q64; wave-local rows only)
  {
    float scale = scale_p[0];
    #pragma unroll
    for (int j = 0; j < 4; ++j) {
      int row = 16*w + hi*4 + j;
      float pv[4];
      float mx = -1e30f;
      #pragma unroll
      for (int fn = 0; fn < 4; ++fn) {
        int col = fn*16 + ln15;
        pv[fn] = sacc[fn][j] + rb[col - row + 63];
        mx = fmaxf(mx, pv[fn]);
      }
      #pragma unroll
      for (int d = 1; d < 16; d <<= 1) mx = fmaxf(mx, __shfl_xor(mx, d));
      float sum = 0.f;
      #pragma unroll
      for (int fn = 0; fn < 4; ++fn) { pv[fn] = __expf(pv[fn] - mx); sum += pv[fn]; }
      #pragma unroll
      for (int d = 1; d < 16; d <<= 1) sum += __shfl_xor(sum, d);
      float inv = scale / sum;
      #pragma unroll
      for (int fn = 0; fn < 4; ++fn) p64[row][fn*16 + ln15] = f2bf(pv[fn] * inv);
    }
  }

  // Phase D: per 64-col chunk: v -> vlds^T -> av = P@V -> avl -> proj
  f32x4 pracc[16] = {};
  for (int cc = 0; cc < 8; ++cc) {
    __syncthreads();                   // vlds overwrite vs prior avl reads
    f32x4 va[4] = {};
    gemm4g(1024 + cc * 64, va);
    #pragma unroll
    for (int fn = 0; fn < 4; ++fn) {
      float bias = sqb[1024 + cc*64 + fn*16 + ln15];
      s16x4 vv;
      #pragma unroll
      for (int j = 0; j < 4; ++j) vv[j] = f2bf(va[fn][j] + bias);
      *reinterpret_cast<s16x4*>(&vlds[fn*16 + ln15][w*16 + hi*4]) = vv;  // V^T
    }
    __syncthreads();                   // vlds visible
    f32x4 pacc[4] = {};
    #pragma unroll
    for (int kk = 0; kk < 2; ++kk) {
      s16x8 ap = *reinterpret_cast<const s16x8*>(&p64[16*w + ln15][kk*32 + hi*8]);
      #pragma unroll
      for (int fn = 0; fn < 4; ++fn) {
        s16x8 bv = *reinterpret_cast<const s16x8*>(&vlds[fn*16 + ln15][kk*32 + hi*8]);
        pacc[fn] = __builtin_amdgcn_mfma_f32_16x16x32_bf16(ap, bv, pacc[fn], 0, 0, 0);
      }
    }
    __syncthreads();                   // vlds reads done -> reuse as avl
    #pragma unroll
    for (int fn = 0; fn < 4; ++fn)
      #pragma unroll
      for (int j = 0; j < 4; ++j)
        avl[w*16 + hi*4 + j][fn*16 + ln15] = f2bf(pacc[fn][j]);
    __syncthreads();                   // avl visible
    #pragma unroll
    for (int kk = 0; kk < 2; ++kk) {
      s16x8 aa = *reinterpret_cast<const s16x8*>(&avl[16*w + ln15][kk*32 + hi*8]);
      #pragma unroll
      for (int fn = 0; fn < 16; ++fn) {
        s16x8 pb = *reinterpret_cast<const s16x8*>(
            &pwTg[(size_t)(fn*16 + ln15)*512 + cc*64 + kk*32 + hi*8]);
        pracc[fn] = __builtin_amdgcn_mfma_f32_16x16x32_bf16(aa, pb, pracc[fn], 0, 0, 0);
      }
    }
  }

  // proj epilogue: +pb, LN over 256 -> ab f32 (constants from global, one-time)
  #pragma unroll
  for (int j = 0; j < 4; ++j) {
    int row = 16*w + hi*4 + j;
    float vv[16];
    float s = 0.f, sq = 0.f;
    #pragma unroll
    for (int fn = 0; fn < 16; ++fn) {
      vv[fn] = pracc[fn][j] + attn_pb[fn*16 + ln15];
      s += vv[fn]; sq += vv[fn]*vv[fn];
    }
    #pragma unroll
    for (int d = 1; d < 16; d <<= 1) { s += __shfl_xor(s, d); sq += __shfl_xor(sq, d); }
    float m = s * (1.f/256.f);
    float rstd = rsqrtf(sq*(1.f/256.f) - m*m + 1e-5f);
    #pragma unroll
    for (int fn = 0; fn < 16; ++fn) {
      int col = fn*16 + ln15;
      ab[((size_t)b*64 + row)*256 + col] = (vv[fn]-m)*rstd*aln_g[col] + aln_b[col];
    }
  }
}

// ---------------------------------------------------------------------------
// Generic bf16-MFMA GEMM for the small GEMMs (pin / pout).
// EPI: 2 = gelu split u/v (pin); 3 = f32 out (+bias +res)
// ---------------------------------------------------------------------------
template<int BM, int BN, int WM, int WN, int EPI>
__global__ __launch_bounds__(256) void gemm_k(
    const short* __restrict__ A, const float* __restrict__ Bw,
    const float* __restrict__ bias, const float* __restrict__ res,
    void* __restrict__ O0, void* __restrict__ O1,
    int M, int N, int K, int Nreal, int Kreal)
{
  constexpr int BK = 64;
  __shared__ __align__(16) short As[BM][BK + 8];
  __shared__ __align__(16) short Bs[BN][BK + 8];
  const int t = threadIdx.x;
  const int lane = t & 63;
  const int w = t >> 6;
  const int wm = w / WN, wn = w % WN;
  const int ln15 = lane & 15, hi = lane >> 4;
  const int m0 = blockIdx.y * BM;
  const int n0 = blockIdx.x * BN;

  f32x4 acc[4][4] = {};

  for (int k0 = 0; k0 < K; k0 += BK) {
    #pragma unroll
    for (int i = 0; i < (BM*BK)/(256*8); ++i) {
      int e = (i*256 + t) * 8;
      int r = e / BK, c = e % BK;
      *reinterpret_cast<i32x4*>(&As[r][c]) =
          *reinterpret_cast<const i32x4*>(&A[(size_t)(m0 + r) * K + k0 + c]);
    }
    #pragma unroll
    for (int i = 0; i < (BK*BN)/256; ++i) {
      int idx = i*256 + t;
      int n = idx % BN, k = idx / BN;
      int gk = k0 + k, gn = n0 + n;
      float v = (gk < Kreal && gn < Nreal) ? Bw[(size_t)gk * Nreal + gn] : 0.f;
      Bs[n][k] = f2bf(v);
    }
    __syncthreads();
    #pragma unroll
    for (int kk = 0; kk < BK; kk += 32) {
      s16x8 af[4], bfr[4];
      #pragma unroll
      for (int fm = 0; fm < 4; ++fm)
        af[fm] = *reinterpret_cast<const s16x8*>(&As[wm*64 + fm*16 + ln15][kk + hi*8]);
      #pragma unroll
      for (int fn = 0; fn < 4; ++fn)
        bfr[fn] = *reinterpret_cast<const s16x8*>(&Bs[wn*64 + fn*16 + ln15][kk + hi*8]);
      #pragma unroll
      for (int fm = 0; fm < 4; ++fm)
        #pragma unroll
        for (int fn = 0; fn < 4; ++fn)
          acc[fm][fn] = __builtin_amdgcn_mfma_f32_16x16x32_bf16(
              af[fm], bfr[fn], acc[fm][fn], 0, 0, 0);
    }
    __syncthreads();
  }

  #pragma unroll
  for (int fm = 0; fm < 4; ++fm) {
    #pragma unroll
    for (int fn = 0; fn < 4; ++fn) {
      #pragma unroll
      for (int j = 0; j < 4; ++j) {
        int row = m0 + wm*64 + fm*16 + hi*4 + j;
        int col = n0 + wn*64 + fn*16 + ln15;
        float v = acc[fm][fn][j];
        if constexpr (EPI == 2) {
          v = gelu_f(v + bias[col]);
          if (col < 256) ((float*)O0)[(size_t)row * 256 + col] = v;
          else ((short*)O1)[(size_t)row * 256 + (col - 256)] = f2bf(v);
        } else { // 3
          v += bias[col] + res[(size_t)row * N + col];
          ((float*)O0)[(size_t)row * N + col] = v;
        }
      }
    }
  }
}

// ---------------------------------------------------------------------------
// K3: LayerNorm over 8192 (mlp_ln) -> bf16, TILE-PACKED output
// ---------------------------------------------------------------------------
__global__ __launch_bounds__(256) void ln8192_k(
    const float* __restrict__ x1,
    const float* __restrict__ g, const float* __restrict__ bb,
    short* __restrict__ lnxp)
{
  __shared__ float red[8];
  int t = threadIdx.x, w = t >> 6, lane = t & 63;
  int b = blockIdx.x;
  const f32x4* xr = reinterpret_cast<const f32x4*>(x1 + (size_t)b * 8192);
  f32x4 vals[8];
  float s = 0.f, sq = 0.f;
  #pragma unroll
  for (int i = 0; i < 8; ++i) {
    f32x4 v = xr[t + i*256];
    vals[i] = v;
    s  += v[0]+v[1]+v[2]+v[3];
    sq += v[0]*v[0]+v[1]*v[1]+v[2]*v[2]+v[3]*v[3];
  }
  s = waveSum(s); sq = waveSum(sq);
  if (lane == 0) { red[w] = s; red[4+w] = sq; }
  __syncthreads();
  s  = red[0]+red[1]+red[2]+red[3];
  sq = red[4]+red[5]+red[6]+red[7];
  float m = s * (1.f/8192.f);
  float rstd = rsqrtf(sq * (1.f/8192.f) - m*m + 1e-5f);
  #pragma unroll
  for (int i = 0; i < 8; ++i) {
    int idx = (t + i*256) * 4;
    f32x4 g4 = reinterpret_cast<const f32x4*>(g)[t + i*256];
    f32x4 b4 = reinterpret_cast<const f32x4*>(bb)[t + i*256];
    s16x4 o;
    #pragma unroll
    for (int k = 0; k < 4; ++k) o[k] = f2bf((vals[i][k]-m)*rstd*g4[k] + b4[k]);
    size_t paddr = ((size_t)(idx >> 6) * 512 + b) * 64 + (idx & 63);
    *reinterpret_cast<s16x4*>(&lnxp[paddr]) = o;
  }
}

// ---------------------------------------------------------------------------
// Split-K GEMM v9 (R13 exact): tile-packed A, B dbuf LDS w/ XOR swizzle,
// write-early/load-late, soft barriers.
// ---------------------------------------------------------------------------
__global__ __launch_bounds__(512, 2) void gemm_splitk9(
    const short* __restrict__ Ap, const float* __restrict__ Bw,
    float* __restrict__ part,
    int N, int K, int Kreal, int ldb, int kchunk, int ntiles)
{
  __shared__ __align__(16) short Bs[2][128 * 64];
  const int t = threadIdx.x, lane = t & 63, w = t >> 6;
  const int ln15 = lane & 15, hi = lane >> 4;
  const int nt = blockIdx.x % ntiles, z = blockIdx.x / ntiles;
  const int n0 = nt * 128;
  const int kbeg = z * kchunk;
  const int kend = (kbeg + kchunk < K) ? (kbeg + kchunk) : K;
  const int nsteps = (kend - kbeg) >> 6;

  const int bn = t & 127;
  const int bg0 = (t >> 7) * 2;
  const bool bok = (n0 + bn) < ldb;
  const int bsw = bn & 7;

  float br[16];
  auto loadB = [&](int k0) {
    const float* bp = Bw + (size_t)(k0 + bg0 * 8) * ldb + n0 + bn;
    #pragma unroll
    for (int m = 0; m < 16; ++m) {
      int gk = k0 + bg0 * 8 + m;
      br[m] = (bok && gk < Kreal) ? bp[(size_t)m * ldb] : 0.f;
    }
  };
  auto writeB = [&](int buf) {
    s16x8 v0, v1;
    #pragma unroll
    for (int m = 0; m < 8; ++m) { v0[m] = f2bf(br[m]); v1[m] = f2bf(br[8 + m]); }
    short* dst = &Bs[buf][bn * 64];
    *reinterpret_cast<s16x8*>(dst + ((bg0    ) ^ bsw) * 8) = v0;
    *reinterpret_cast<s16x8*>(dst + ((bg0 + 1) ^ bsw) * 8) = v1;
  };

  f32x4 acc[4][8] = {};

  loadB(kbeg);
  writeB(0);
  if (nsteps > 1) loadB(kbeg + 64);
  softBarrier();

  for (int s = 0; s < nsteps; ++s) {
    const int k0 = kbeg + s * 64;
    const short* atile = Ap + (size_t)(k0 >> 6) * 512 * 64;
    s16x8 af[8];
    #pragma unroll
    for (int kk = 0; kk < 2; ++kk)
      #pragma unroll
      for (int fm = 0; fm < 4; ++fm) {
        int row = w * 64 + fm * 16 + ln15;
        af[kk * 4 + fm] = *reinterpret_cast<const s16x8*>(
            &atile[row * 64 + (kk * 4 + hi) * 8]);
      }
    if (s + 1 < nsteps) writeB((s + 1) & 1);
    if (s + 2 < nsteps) loadB(kbeg + (s + 2) * 64);

    const short* bsrc = &Bs[s & 1][0];
    #pragma unroll
    for (int kk = 0; kk < 2; ++kk) {
      const int g = kk * 4 + hi;
      #pragma unroll
      for (int fn = 0; fn < 8; ++fn) {
        int row = fn * 16 + ln15;
        s16x8 bv = *reinterpret_cast<const s16x8*>(
            &bsrc[row * 64 + ((g ^ (row & 7)) * 8)]);
        #pragma unroll
        for (int fm = 0; fm < 4; ++fm)
          acc[fm][fn] = __builtin_amdgcn_mfma_f32_16x16x32_bf16(
              af[kk * 4 + fm], bv, acc[fm][fn], 0, 0, 0);
      }
    }
    softBarrier();
  }

  #pragma unroll
  for (int fm = 0; fm < 4; ++fm)
    #pragma unroll
    for (int fn = 0; fn < 8; ++fn)
      #pragma unroll
      for (int j = 0; j < 4; ++j) {
        int row = w * 64 + fm * 16 + hi * 4 + j;
        int col = n0 + fn * 16 + ln15;
        part[((size_t)z * 512 + row) * N + col] = acc[fm][fn][j];
      }
}

// ---------------------------------------------------------------------------
// split-K reduce for mlp1: h3 = gelu(sum part + b1), bf16, TILE-PACKED out
// ---------------------------------------------------------------------------
__global__ __launch_bounds__(256) void reduce_mlp1_k(
    const float* __restrict__ part, const float* __restrict__ bias,
    short* __restrict__ h3p, int N, int Nreal, int M, int ks)
{
  int col4 = (blockIdx.x * 256 + threadIdx.x) * 4;
  int row = blockIdx.y;
  if (col4 >= N) return;
  size_t base = (size_t)row * N + col4;
  size_t stride = (size_t)M * N;
  f32x4 s = *reinterpret_cast<const f32x4*>(part + base);
  for (int k = 1; k < ks; ++k)
    s += *reinterpret_cast<const f32x4*>(part + base + (size_t)k * stride);
  s16x4 o;
  #pragma unroll
  for (int j = 0; j < 4; ++j) {
    int c = col4 + j;
    float v = 0.f;
    if (c < Nreal) v = gelu_f(s[j] + bias[c]);
    o[j] = f2bf(v);
  }
  size_t paddr = ((size_t)(col4 >> 6) * 512 + row) * 64 + (col4 & 63);
  *reinterpret_cast<s16x4*>(&h3p[paddr]) = o;
}

// ---------------------------------------------------------------------------
// split-K reduce for mlp2: out = sum part + b2 + x1 (f32)
// ---------------------------------------------------------------------------
__global__ __launch_bounds__(256) void reduce_mlp2_k(
    const float* __restrict__ part, const float* __restrict__ bias,
    const float* __restrict__ x1, float* __restrict__ out, int N, int M, int ks)
{
  int col4 = (blockIdx.x * 256 + threadIdx.x) * 4;
  int row = blockIdx.y;
  size_t base = (size_t)row * N + col4;
  size_t stride = (size_t)M * N;
  f32x4 s = *reinterpret_cast<const f32x4*>(part + base);
  for (int k = 1; k < ks; ++k)
    s += *reinterpret_cast<const f32x4*>(part + base + (size_t)k * stride);
  f32x4 b4 = *reinterpret_cast<const f32x4*>(bias + col4);
  f32x4 r4 = *reinterpret_cast<const f32x4*>(x1 + base);
  #pragma unroll
  for (int j = 0; j < 4; ++j) s[j] += b4[j] + r4[j];
  *reinterpret_cast<f32x4*>(out + base) = s;
}

// ---------------------------------------------------------------------------
// K5: SGU gate (unchanged)
// ---------------------------------------------------------------------------
__global__ __launch_bounds__(256) void gate_k(
    const float* __restrict__ u, const short* __restrict__ vbf,
    const float* __restrict__ a,
    const float* __restrict__ spg_g, const float* __restrict__ spg_b,
    const float* __restrict__ spw, const float* __restrict__ spb,
    const float* __restrict__ pog, const float* __restrict__ pob,
    short* __restrict__ outn)
{
  __shared__ __align__(16) short nvb[256][72];
  __shared__ __align__(16) short spwT[64][72];
  __shared__ float s_spg[64], s_spbl[64], s_spb[64];
  __shared__ float s_pog[256], s_pob[256];
  int t = threadIdx.x, lane = t & 63, w = t >> 6;
  int ln15 = lane & 15, hi = lane >> 4;
  int b = blockIdx.x;

  if (t < 64) { s_spg[t] = spg_g[t]; s_spbl[t] = spg_b[t]; s_spb[t] = spb[t]; }
  s_pog[t] = pog[t]; s_pob[t] = pob[t];
  #pragma unroll
  for (int i = 0; i < 16; ++i) {
    int idx = i*256 + t;
    int sr = idx >> 6, tc = idx & 63;
    spwT[tc][sr] = f2bf(spw[idx]);
  }

  float vvv[64];
  {
    int c = t;
    float s = 0.f, sq = 0.f;
    #pragma unroll
    for (int si = 0; si < 64; ++si) {
      float f = bf2f(vbf[(size_t)(b*64 + si) * 256 + c]);
      vvv[si] = f; s += f; sq += f*f;
    }
    float m = s * (1.f/64.f);
    float rstd = rsqrtf(sq * (1.f/64.f) - m*m + 1e-5f);
    __syncthreads();
    #pragma unroll
    for (int si = 0; si < 64; ++si)
      nvb[c][si] = f2bf((vvv[si]-m)*rstd*s_spg[si] + s_spbl[si]);
  }
  __syncthreads();

  f32x4 yacc[4][4] = {};
  #pragma unroll
  for (int kk = 0; kk < 64; kk += 32) {
    s16x8 af[4], bfr[4];
    #pragma unroll
    for (int fm = 0; fm < 4; ++fm)
      af[fm] = *reinterpret_cast<const s16x8*>(&nvb[64*w + fm*16 + ln15][kk + hi*8]);
    #pragma unroll
    for (int fn = 0; fn < 4; ++fn)
      bfr[fn] = *reinterpret_cast<const s16x8*>(&spwT[fn*16 + ln15][kk + hi*8]);
    #pragma unroll
    for (int fm = 0; fm < 4; ++fm)
      #pragma unroll
      for (int fn = 0; fn < 4; ++fn)
        yacc[fm][fn] = __builtin_amdgcn_mfma_f32_16x16x32_bf16(
            af[fm], bfr[fn], yacc[fm][fn], 0, 0, 0);
  }
  __syncthreads();

  short (*outl)[264] = reinterpret_cast<short(*)[264]>(&nvb[0][0]);
  #pragma unroll
  for (int fm = 0; fm < 4; ++fm) {
    #pragma unroll
    for (int fn = 0; fn < 4; ++fn) {
      int crow = 64*w + fm*16 + hi*4;
      int tcol = fn*16 + ln15;
      f32x4 u4 = *reinterpret_cast<const f32x4*>(&u[(size_t)(b*64 + tcol)*256 + crow]);
      f32x4 a4 = *reinterpret_cast<const f32x4*>(&a[(size_t)(b*64 + tcol)*256 + crow]);
      #pragma unroll
      for (int j = 0; j < 4; ++j) {
        float g = gelu_f(yacc[fm][fn][j] + s_spb[tcol]);
        float o = u4[j] * (g + a4[j]);
        outl[tcol][crow + j] = f2bf(o);
      }
    }
  }
  __syncthreads();

  #pragma unroll
  for (int ri = 0; ri < 16; ++ri) {
    int trow = w*16 + ri;
    int c = lane * 4;
    s16x4 raw = *reinterpret_cast<const s16x4*>(&outl[trow][c]);
    float f0 = bf2f(raw[0]), f1 = bf2f(raw[1]), f2 = bf2f(raw[2]), f3 = bf2f(raw[3]);
    float s  = f0+f1+f2+f3;
    float sq = f0*f0+f1*f1+f2*f2+f3*f3;
    s = waveSum(s); sq = waveSum(sq);
    float m = s * (1.f/256.f);
    float rstd = rsqrtf(sq * (1.f/256.f) - m*m + 1e-5f);
    s16x4 o;
    o[0] = f2bf((f0-m)*rstd*s_pog[c+0] + s_pob[c+0]);
    o[1] = f2bf((f1-m)*rstd*s_pog[c+1] + s_pob[c+1]);
    o[2] = f2bf((f2-m)*rstd*s_pog[c+2] + s_pob[c+2]);
    o[3] = f2bf((f3-m)*rstd*s_pog[c+3] + s_pob[c+3]);
    *reinterpret_cast<s16x4*>(&outn[(size_t)(b*64 + trow)*256 + c]) = o;
  }
}

// ---------------------------------------------------------------------------
extern "C" void kernel_launch(void* const* d_in, const int* in_sizes, int n_in,
                              void* d_out, int out_size, void* d_ws, size_t ws_size,
                              hipStream_t stream)
{
  const float* x          = (const float*)d_in[0];
  const float* qkv_ln_g   = (const float*)d_in[1];
  const float* qkv_ln_b   = (const float*)d_in[2];
  const float* qkv_w      = (const float*)d_in[3];
  const float* qkv_b      = (const float*)d_in[4];
  const float* attn_pw    = (const float*)d_in[5];
  const float* attn_pb    = (const float*)d_in[6];
  const float* attn_ln_g  = (const float*)d_in[7];
  const float* attn_ln_b  = (const float*)d_in[8];
  const float* rel_bias   = (const float*)d_in[9];
  const float* scale      = (const float*)d_in[10];
  const float* pin_ln_g   = (const float*)d_in[11];
  const float* pin_ln_b   = (const float*)d_in[12];
  const float* pin_w      = (const float*)d_in[13];
  const float* pin_b      = (const float*)d_in[14];
  const float* sp_ln_g    = (const float*)d_in[15];
  const float* sp_ln_b    = (const float*)d_in[16];
  const float* sp_w       = (const float*)d_in[17];
  const float* sp_b       = (const float*)d_in[18];
  const float* pout_ln_g  = (const float*)d_in[19];
  const float* pout_ln_b  = (const float*)d_in[20];
  const float* pout_w     = (const float*)d_in[21];
  const float* pout_b     = (const float*)d_in[22];
  const float* mlp_ln_g   = (const float*)d_in[23];
  const float* mlp_ln_b   = (const float*)d_in[24];
  const float* mlp_w1     = (const float*)d_in[25];
  const float* mlp_b1     = (const float*)d_in[26];
  const float* mlp_w2     = (const float*)d_in[27];
  const float* mlp_b2     = (const float*)d_in[28];

  char* ws = (char*)d_ws;
  short* lnp   = (short*)(ws + 0);           // 8.39 MB (dead after pin gemm)
  float* x1b   = (float*)(ws + 0);           // 16.78 MB (written at pout)
  float* ab    = (float*)(ws + 16777216);    // 33.55 MB f32
  float* ub    = (float*)(ws + 50331648);    // 33.55 MB f32
  short* wTg   = (short*)(ws + 83886080);    // 393 KB (pre-pin region)
  short* pwTg  = (short*)(ws + 84279296);    // 262 KB
  short* vbfb  = (short*)(ws + 83886080);    // 16.78 MB bf16 (after fused)
  short* outnb = (short*)(ws + 100663296);   // 16.78 MB bf16
  short* lnxp  = (short*)(ws + 150994944);   // 8.39 MB (tile-packed)
  short* h3p   = (short*)(ws + 159383552);   // 9.31 MB (tile-packed)
  float* partb = (float*)(ws + 16777216);    // split-K partials (<=74.5 MB)

  // weight transpose (once) -> wTg, pwTg
  prep_w_k<<<160, 256, 0, stream>>>(qkv_w, attn_pw, wTg, pwTg);
  // fused: LN + qkv + attention + proj + ln256  ->  lnp, ab
  fused_attn_k<<<512, 256, 0, stream>>>(
      x, qkv_ln_g, qkv_ln_b, pin_ln_g, pin_ln_b, wTg, qkv_b,
      pwTg, attn_pb, attn_ln_g, attn_ln_b, rel_bias, scale, lnp, ab);
  // pin: [32768,128]@[128,512]+b, gelu, split u (f32) / v (bf16)
  gemm_k<128,128,2,2,2><<<dim3(4,256), 256, 0, stream>>>(
      lnp, pin_w, pin_b, nullptr, ub, vbfb, 32768, 512, 128, 512, 128);
  // SGU gate + fused pout_ln -> outn bf16
  gate_k<<<512, 256, 0, stream>>>(ub, vbfb, ab, sp_ln_g, sp_ln_b, sp_w, sp_b,
                                  pout_ln_g, pout_ln_b, outnb);
  // pout: [32768,256]@[256,128]+b + x residual -> x1 f32
  gemm_k<128,128,2,2,3><<<dim3(1,256), 256, 0, stream>>>(
      outnb, pout_w, pout_b, x, x1b, nullptr, 32768, 128, 256, 128, 256);
  // LN over 8192 -> lnx (tile-packed)
  ln8192_k<<<512, 256, 0, stream>>>(x1b, mlp_ln_g, mlp_ln_b, lnxp);

  // mlp1: [512,8192] @ [8192,9011] (N padded 9088), split-K 3, 213 blocks
  gemm_splitk9<<<213, 512, 0, stream>>>(
      lnxp, mlp_w1, partb, /*N=*/9088, /*K=*/8192, /*Kreal=*/8192,
      /*ldb=*/9011, /*kchunk=*/2752, /*ntiles=*/71);
  reduce_mlp1_k<<<dim3(9, 512), 256, 0, stream>>>(partb, mlp_b1, h3p, 9088, 9011, 512, 3);

  // mlp2: [512,9088] @ [9011,8192], split-K 4, 256 blocks
  gemm_splitk9<<<256, 512, 0, stream>>>(
      h3p, mlp_w2, partb, /*N=*/8192, /*K=*/9088, /*Kreal=*/9011,
      /*ldb=*/8192, /*kchunk=*/2304, /*ntiles=*/64);
  reduce_mlp2_k<<<dim3(8, 512), 256, 0, stream>>>(partb, mlp_b2, x1b, (float*)d_out, 8192, 512, 4);
}

// Round 16
// 648.662 us; speedup vs baseline: 2.3610x; 1.0314x over previous
//
#include <hip/hip_runtime.h>
#include <hip/hip_bf16.h>
#include <math.h>

typedef float f32x4 __attribute__((ext_vector_type(4)));
typedef float f32x2 __attribute__((ext_vector_type(2)));
typedef short s16x8 __attribute__((ext_vector_type(8)));
typedef short s16x4 __attribute__((ext_vector_type(4)));
typedef int   i32x4 __attribute__((ext_vector_type(4)));

__device__ __forceinline__ short f2bf(float f) {
  __hip_bfloat16 h = __float2bfloat16(f);
  return __builtin_bit_cast(short, h);
}
__device__ __forceinline__ float bf2f(short s) {
  __hip_bfloat16 h = __builtin_bit_cast(__hip_bfloat16, s);
  return __bfloat162float(h);
}
__device__ __forceinline__ float gelu_f(float x) {
  return 0.5f * x * (1.f + erff(x * 0.70710678118654752440f));
}
__device__ __forceinline__ float waveSum(float v) {
  #pragma unroll
  for (int d = 32; d; d >>= 1) v += __shfl_xor(v, d);
  return v;
}
// Soft barrier: LDS-visibility only; does NOT drain vmcnt.
__device__ __forceinline__ void softBarrier() {
  asm volatile("s_waitcnt lgkmcnt(0)" ::: "memory");
  __builtin_amdgcn_s_barrier();
  asm volatile("" ::: "memory");
}

// ---------------------------------------------------------------------------
// P0: one-shot weight transpose to bf16 (attention weights).
// wTg[1536][128]  = qkv_w^T   (row = output col, 128 k each)
// pwTg[256][512]  = attn_pw^T (row = output col, 512 k each)
// ---------------------------------------------------------------------------
__global__ __launch_bounds__(256) void prep_w_k(
    const float* __restrict__ qkv_w, const float* __restrict__ attn_pw,
    short* __restrict__ wTg, short* __restrict__ pwTg)
{
  int idx = blockIdx.x * 256 + threadIdx.x;
  if (idx < 24576) {                 // 1536*128/8
    int r = idx >> 4;
    int k0 = (idx & 15) * 8;
    s16x8 v;
    #pragma unroll
    for (int m = 0; m < 8; ++m) v[m] = f2bf(qkv_w[(size_t)(k0 + m) * 1536 + r]);
    *reinterpret_cast<s16x8*>(&wTg[r * 128 + k0]) = v;
  } else if (idx < 24576 + 16384) {  // 256*512/8
    int e = idx - 24576;
    int r = e >> 6;
    int k0 = (e & 63) * 8;
    s16x8 v;
    #pragma unroll
    for (int m = 0; m < 8; ++m) v[m] = f2bf(attn_pw[(size_t)(k0 + m) * 256 + r]);
    *reinterpret_cast<s16x8*>(&pwTg[r * 512 + k0]) = v;
  }
}

// ---------------------------------------------------------------------------
// F1 (R13 exact): fused per-board attention branch; weights read as MFMA
// B-fragments directly from the pre-transposed global buffers (L2-resident).
// LDS = 71.5 KB -> 2 blocks/CU.  q,k computed in 64-col chunks (q64/k64),
// v/proj in 128-col chunks.  Best-measured variant (170 us).
// ---------------------------------------------------------------------------
__global__ __launch_bounds__(256, 2) void fused_attn_k(
    const float* __restrict__ x,
    const float* __restrict__ qln_g, const float* __restrict__ qln_b,
    const float* __restrict__ pln_g, const float* __restrict__ pln_b,
    const short* __restrict__ wTg, const float* __restrict__ qkv_b,
    const short* __restrict__ pwTg, const float* __restrict__ attn_pb,
    const float* __restrict__ aln_g, const float* __restrict__ aln_b,
    const float* __restrict__ relb, const float* __restrict__ scale_p,
    short* __restrict__ lnp, float* __restrict__ ab)
{
  __shared__ __align__(16) char arena[73216];
  short (*lnq)[136] = reinterpret_cast<short(*)[136]>(arena + 0);      // 17408
  short (*vlds)[72] = reinterpret_cast<short(*)[72]>(arena + 17408);   // 18432
  short (*avl)[136] = reinterpret_cast<short(*)[136]>(arena + 17408);  // alias
  short (*q64)[72]  = reinterpret_cast<short(*)[72]>(arena + 35840);   // 9216
  short (*k64)[72]  = reinterpret_cast<short(*)[72]>(arena + 45056);   // 9216
  short (*p64)[72]  = reinterpret_cast<short(*)[72]>(arena + 54272);   // 9216
  float* sqb  = reinterpret_cast<float*>(arena + 63488);  // 1536 f32
  float* rb   = reinterpret_cast<float*>(arena + 69632);  // 127 f32
  float* sapb = reinterpret_cast<float*>(arena + 70144);  // 256
  float* sag  = reinterpret_cast<float*>(arena + 71168);  // 256
  float* sab2 = reinterpret_cast<float*>(arena + 72192);  // 256

  const int t = threadIdx.x, lane = t & 63, w = t >> 6;
  const int ln15 = lane & 15, hi = lane >> 4;
  const int b = blockIdx.x;

  if (t < 127) rb[t] = relb[t];
  sapb[t] = attn_pb[t]; sag[t] = aln_g[t]; sab2[t] = aln_b[t];
  #pragma unroll
  for (int i = 0; i < 6; ++i) sqb[i*256 + t] = qkv_b[i*256 + t];

  // Phase A: row LN -> lnq (LDS bf16) and lnp (global bf16)
  {
    int c = lane * 2;
    float qg0 = qln_g[c], qg1 = qln_g[c+1], qb0 = qln_b[c], qb1 = qln_b[c+1];
    float pg0 = pln_g[c], pg1 = pln_g[c+1], pb0 = pln_b[c], pb1 = pln_b[c+1];
    for (int i = 0; i < 16; ++i) {
      int r = w * 16 + i;
      f32x2 v = *reinterpret_cast<const f32x2*>(&x[((size_t)b*64 + r)*128 + c]);
      float s = v[0] + v[1], sq = v[0]*v[0] + v[1]*v[1];
      s = waveSum(s); sq = waveSum(sq);
      float m = s * (1.f/128.f);
      float rstd = rsqrtf(sq*(1.f/128.f) - m*m + 1e-5f);
      float a0 = (v[0]-m)*rstd, a1 = (v[1]-m)*rstd;
      unsigned u0 = (unsigned short)f2bf(a0*qg0 + qb0);
      unsigned u1 = (unsigned short)f2bf(a1*qg1 + qb1);
      *reinterpret_cast<unsigned*>(&lnq[r][c]) = u0 | (u1 << 16);
      unsigned p0 = (unsigned short)f2bf(a0*pg0 + pb0);
      unsigned p1 = (unsigned short)f2bf(a1*pg1 + pb1);
      ((unsigned*)lnp)[((size_t)b*64 + r)*64 + lane] = p0 | (p1 << 16);
    }
  }
  __syncthreads();

  // out(64 x 64chunk) = lnq @ wTg[coff..] : B-frags direct from global
  auto gemm4g = [&](int coff, f32x4 (&acc)[4]) {
    #pragma unroll
    for (int kk = 0; kk < 4; ++kk) {
      s16x8 af = *reinterpret_cast<const s16x8*>(&lnq[w*16 + ln15][kk*32 + hi*8]);
      #pragma unroll
      for (int fn = 0; fn < 4; ++fn) {
        int col = coff + fn*16 + ln15;
        s16x8 bf = *reinterpret_cast<const s16x8*>(&wTg[(size_t)col*128 + kk*32 + hi*8]);
        acc[fn] = __builtin_amdgcn_mfma_f32_16x16x32_bf16(af, bf, acc[fn], 0, 0, 0);
      }
    }
  };
  auto gemm8g = [&](int coff, f32x4 (&acc)[8]) {
    #pragma unroll
    for (int kk = 0; kk < 4; ++kk) {
      s16x8 af = *reinterpret_cast<const s16x8*>(&lnq[w*16 + ln15][kk*32 + hi*8]);
      #pragma unroll
      for (int fn = 0; fn < 8; ++fn) {
        int col = coff + fn*16 + ln15;
        s16x8 bf = *reinterpret_cast<const s16x8*>(&wTg[(size_t)col*128 + kk*32 + hi*8]);
        acc[fn] = __builtin_amdgcn_mfma_f32_16x16x32_bf16(af, bf, acc[fn], 0, 0, 0);
      }
    }
  };

  // Phase B: scores = q @ k^T over 8 x 64-d chunks
  f32x4 sacc[4] = {};
  for (int kc = 0; kc < 8; ++kc) {
    __syncthreads();                   // q64/k64 overwrite vs prior QK reads
    f32x4 qa[4] = {};
    gemm4g(kc * 64, qa);
    #pragma unroll
    for (int fn = 0; fn < 4; ++fn) {
      float bias = sqb[kc*64 + fn*16 + ln15];
      #pragma unroll
      for (int j = 0; j < 4; ++j)
        q64[w*16 + hi*4 + j][fn*16 + ln15] = f2bf(qa[fn][j] + bias);
    }
    f32x4 ka[4] = {};
    gemm4g(512 + kc * 64, ka);
    #pragma unroll
    for (int fn = 0; fn < 4; ++fn) {
      float bias = sqb[512 + kc*64 + fn*16 + ln15];
      #pragma unroll
      for (int j = 0; j < 4; ++j)
        k64[w*16 + hi*4 + j][fn*16 + ln15] = f2bf(ka[fn][j] + bias);
    }
    __syncthreads();                   // q64/k64 visible
    #pragma unroll
    for (int kk = 0; kk < 2; ++kk) {
      s16x8 aq = *reinterpret_cast<const s16x8*>(&q64[16*w + ln15][kk*32 + hi*8]);
      #pragma unroll
      for (int fn = 0; fn < 4; ++fn) {
        s16x8 bk = *reinterpret_cast<const s16x8*>(&k64[fn*16 + ln15][kk*32 + hi*8]);
        sacc[fn] = __builtin_amdgcn_mfma_f32_16x16x32_bf16(aq, bk, sacc[fn], 0, 0, 0);
      }
    }
  }

  // softmax + post-softmax scale -> p64 bf16 (wave-local rows)
  {
    float scale = scale_p[0];
    #pragma unroll
    for (int j = 0; j < 4; ++j) {
      int row = 16*w + hi*4 + j;
      float pv[4];
      float mx = -1e30f;
      #pragma unroll
      for (int fn = 0; fn < 4; ++fn) {
        int col = fn*16 + ln15;
        pv[fn] = sacc[fn][j] + rb[col - row + 63];
        mx = fmaxf(mx, pv[fn]);
      }
      #pragma unroll
      for (int d = 1; d < 16; d <<= 1) mx = fmaxf(mx, __shfl_xor(mx, d));
      float sum = 0.f;
      #pragma unroll
      for (int fn = 0; fn < 4; ++fn) { pv[fn] = __expf(pv[fn] - mx); sum += pv[fn]; }
      #pragma unroll
      for (int d = 1; d < 16; d <<= 1) sum += __shfl_xor(sum, d);
      float inv = scale / sum;
      #pragma unroll
      for (int fn = 0; fn < 4; ++fn) p64[row][fn*16 + ln15] = f2bf(pv[fn] * inv);
    }
  }

  // Phase D: per 128-col chunk: v -> vlds^T -> av = P@V -> avl -> proj
  f32x4 pracc[16] = {};
  for (int cc = 0; cc < 4; ++cc) {
    __syncthreads();                   // vlds overwrite vs prior avl reads
    f32x4 va[8] = {};
    gemm8g(1024 + cc * 128, va);
    #pragma unroll
    for (int fn = 0; fn < 8; ++fn) {
      float bias = sqb[1024 + cc*128 + fn*16 + ln15];
      s16x4 vv;
      #pragma unroll
      for (int j = 0; j < 4; ++j) vv[j] = f2bf(va[fn][j] + bias);
      *reinterpret_cast<s16x4*>(&vlds[fn*16 + ln15][w*16 + hi*4]) = vv;  // V^T
    }
    __syncthreads();                   // vlds visible (p64 also)
    f32x4 pacc[8] = {};
    #pragma unroll
    for (int kk = 0; kk < 2; ++kk) {
      s16x8 ap = *reinterpret_cast<const s16x8*>(&p64[16*w + ln15][kk*32 + hi*8]);
      #pragma unroll
      for (int fn = 0; fn < 8; ++fn) {
        s16x8 bv = *reinterpret_cast<const s16x8*>(&vlds[fn*16 + ln15][kk*32 + hi*8]);
        pacc[fn] = __builtin_amdgcn_mfma_f32_16x16x32_bf16(ap, bv, pacc[fn], 0, 0, 0);
      }
    }
    __syncthreads();                   // vlds reads done -> reuse as avl
    #pragma unroll
    for (int fn = 0; fn < 8; ++fn)
      #pragma unroll
      for (int j = 0; j < 4; ++j)
        avl[w*16 + hi*4 + j][fn*16 + ln15] = f2bf(pacc[fn][j]);
    __syncthreads();                   // avl visible
    #pragma unroll
    for (int kk = 0; kk < 4; ++kk) {
      s16x8 aa = *reinterpret_cast<const s16x8*>(&avl[16*w + ln15][kk*32 + hi*8]);
      #pragma unroll
      for (int fn = 0; fn < 16; ++fn) {
        s16x8 pb = *reinterpret_cast<const s16x8*>(
            &pwTg[(size_t)(fn*16 + ln15)*512 + cc*128 + kk*32 + hi*8]);
        pracc[fn] = __builtin_amdgcn_mfma_f32_16x16x32_bf16(aa, pb, pracc[fn], 0, 0, 0);
      }
    }
  }

  // proj epilogue: +pb, LN over 256 -> ab f32
  #pragma unroll
  for (int j = 0; j < 4; ++j) {
    int row = 16*w + hi*4 + j;
    float vv[16];
    float s = 0.f, sq = 0.f;
    #pragma unroll
    for (int fn = 0; fn < 16; ++fn) {
      vv[fn] = pracc[fn][j] + sapb[fn*16 + ln15];
      s += vv[fn]; sq += vv[fn]*vv[fn];
    }
    #pragma unroll
    for (int d = 1; d < 16; d <<= 1) { s += __shfl_xor(s, d); sq += __shfl_xor(sq, d); }
    float m = s * (1.f/256.f);
    float rstd = rsqrtf(sq*(1.f/256.f) - m*m + 1e-5f);
    #pragma unroll
    for (int fn = 0; fn < 16; ++fn) {
      int col = fn*16 + ln15;
      ab[((size_t)b*64 + row)*256 + col] = (vv[fn]-m)*rstd*sag[col] + sab2[col];
    }
  }
}

// ---------------------------------------------------------------------------
// Generic bf16-MFMA GEMM for the small GEMMs (pin / pout).
// EPI: 2 = gelu split u/v (pin); 3 = f32 out (+bias +res)
// ---------------------------------------------------------------------------
template<int BM, int BN, int WM, int WN, int EPI>
__global__ __launch_bounds__(256) void gemm_k(
    const short* __restrict__ A, const float* __restrict__ Bw,
    const float* __restrict__ bias, const float* __restrict__ res,
    void* __restrict__ O0, void* __restrict__ O1,
    int M, int N, int K, int Nreal, int Kreal)
{
  constexpr int BK = 64;
  __shared__ __align__(16) short As[BM][BK + 8];
  __shared__ __align__(16) short Bs[BN][BK + 8];
  const int t = threadIdx.x;
  const int lane = t & 63;
  const int w = t >> 6;
  const int wm = w / WN, wn = w % WN;
  const int ln15 = lane & 15, hi = lane >> 4;
  const int m0 = blockIdx.y * BM;
  const int n0 = blockIdx.x * BN;

  f32x4 acc[4][4] = {};

  for (int k0 = 0; k0 < K; k0 += BK) {
    #pragma unroll
    for (int i = 0; i < (BM*BK)/(256*8); ++i) {
      int e = (i*256 + t) * 8;
      int r = e / BK, c = e % BK;
      *reinterpret_cast<i32x4*>(&As[r][c]) =
          *reinterpret_cast<const i32x4*>(&A[(size_t)(m0 + r) * K + k0 + c]);
    }
    #pragma unroll
    for (int i = 0; i < (BK*BN)/256; ++i) {
      int idx = i*256 + t;
      int n = idx % BN, k = idx / BN;
      int gk = k0 + k, gn = n0 + n;
      float v = (gk < Kreal && gn < Nreal) ? Bw[(size_t)gk * Nreal + gn] : 0.f;
      Bs[n][k] = f2bf(v);
    }
    __syncthreads();
    #pragma unroll
    for (int kk = 0; kk < BK; kk += 32) {
      s16x8 af[4], bfr[4];
      #pragma unroll
      for (int fm = 0; fm < 4; ++fm)
        af[fm] = *reinterpret_cast<const s16x8*>(&As[wm*64 + fm*16 + ln15][kk + hi*8]);
      #pragma unroll
      for (int fn = 0; fn < 4; ++fn)
        bfr[fn] = *reinterpret_cast<const s16x8*>(&Bs[wn*64 + fn*16 + ln15][kk + hi*8]);
      #pragma unroll
      for (int fm = 0; fm < 4; ++fm)
        #pragma unroll
        for (int fn = 0; fn < 4; ++fn)
          acc[fm][fn] = __builtin_amdgcn_mfma_f32_16x16x32_bf16(
              af[fm], bfr[fn], acc[fm][fn], 0, 0, 0);
    }
    __syncthreads();
  }

  #pragma unroll
  for (int fm = 0; fm < 4; ++fm) {
    #pragma unroll
    for (int fn = 0; fn < 4; ++fn) {
      #pragma unroll
      for (int j = 0; j < 4; ++j) {
        int row = m0 + wm*64 + fm*16 + hi*4 + j;
        int col = n0 + wn*64 + fn*16 + ln15;
        float v = acc[fm][fn][j];
        if constexpr (EPI == 2) {
          v = gelu_f(v + bias[col]);
          if (col < 256) ((float*)O0)[(size_t)row * 256 + col] = v;
          else ((short*)O1)[(size_t)row * 256 + (col - 256)] = f2bf(v);
        } else { // 3
          v += bias[col] + res[(size_t)row * N + col];
          ((float*)O0)[(size_t)row * N + col] = v;
        }
      }
    }
  }
}

// ---------------------------------------------------------------------------
// K3: LayerNorm over 8192 (mlp_ln) -> bf16, TILE-PACKED output
// ---------------------------------------------------------------------------
__global__ __launch_bounds__(256) void ln8192_k(
    const float* __restrict__ x1,
    const float* __restrict__ g, const float* __restrict__ bb,
    short* __restrict__ lnxp)
{
  __shared__ float red[8];
  int t = threadIdx.x, w = t >> 6, lane = t & 63;
  int b = blockIdx.x;
  const f32x4* xr = reinterpret_cast<const f32x4*>(x1 + (size_t)b * 8192);
  f32x4 vals[8];
  float s = 0.f, sq = 0.f;
  #pragma unroll
  for (int i = 0; i < 8; ++i) {
    f32x4 v = xr[t + i*256];
    vals[i] = v;
    s  += v[0]+v[1]+v[2]+v[3];
    sq += v[0]*v[0]+v[1]*v[1]+v[2]*v[2]+v[3]*v[3];
  }
  s = waveSum(s); sq = waveSum(sq);
  if (lane == 0) { red[w] = s; red[4+w] = sq; }
  __syncthreads();
  s  = red[0]+red[1]+red[2]+red[3];
  sq = red[4]+red[5]+red[6]+red[7];
  float m = s * (1.f/8192.f);
  float rstd = rsqrtf(sq * (1.f/8192.f) - m*m + 1e-5f);
  #pragma unroll
  for (int i = 0; i < 8; ++i) {
    int idx = (t + i*256) * 4;
    f32x4 g4 = reinterpret_cast<const f32x4*>(g)[t + i*256];
    f32x4 b4 = reinterpret_cast<const f32x4*>(bb)[t + i*256];
    s16x4 o;
    #pragma unroll
    for (int k = 0; k < 4; ++k) o[k] = f2bf((vals[i][k]-m)*rstd*g4[k] + b4[k]);
    size_t paddr = ((size_t)(idx >> 6) * 512 + b) * 64 + (idx & 63);
    *reinterpret_cast<s16x4*>(&lnxp[paddr]) = o;
  }
}

// ---------------------------------------------------------------------------
// Split-K GEMM v9 (R13 exact): tile-packed A, B dbuf LDS w/ XOR swizzle,
// write-early/load-late, soft barriers.
// ---------------------------------------------------------------------------
__global__ __launch_bounds__(512, 2) void gemm_splitk9(
    const short* __restrict__ Ap, const float* __restrict__ Bw,
    float* __restrict__ part,
    int N, int K, int Kreal, int ldb, int kchunk, int ntiles)
{
  __shared__ __align__(16) short Bs[2][128 * 64];
  const int t = threadIdx.x, lane = t & 63, w = t >> 6;
  const int ln15 = lane & 15, hi = lane >> 4;
  const int nt = blockIdx.x % ntiles, z = blockIdx.x / ntiles;
  const int n0 = nt * 128;
  const int kbeg = z * kchunk;
  const int kend = (kbeg + kchunk < K) ? (kbeg + kchunk) : K;
  const int nsteps = (kend - kbeg) >> 6;

  const int bn = t & 127;
  const int bg0 = (t >> 7) * 2;
  const bool bok = (n0 + bn) < ldb;
  const int bsw = bn & 7;

  float br[16];
  auto loadB = [&](int k0) {
    const float* bp = Bw + (size_t)(k0 + bg0 * 8) * ldb + n0 + bn;
    #pragma unroll
    for (int m = 0; m < 16; ++m) {
      int gk = k0 + bg0 * 8 + m;
      br[m] = (bok && gk < Kreal) ? bp[(size_t)m * ldb] : 0.f;
    }
  };
  auto writeB = [&](int buf) {
    s16x8 v0, v1;
    #pragma unroll
    for (int m = 0; m < 8; ++m) { v0[m] = f2bf(br[m]); v1[m] = f2bf(br[8 + m]); }
    short* dst = &Bs[buf][bn * 64];
    *reinterpret_cast<s16x8*>(dst + ((bg0    ) ^ bsw) * 8) = v0;
    *reinterpret_cast<s16x8*>(dst + ((bg0 + 1) ^ bsw) * 8) = v1;
  };

  f32x4 acc[4][8] = {};

  loadB(kbeg);
  writeB(0);
  if (nsteps > 1) loadB(kbeg + 64);
  softBarrier();

  for (int s = 0; s < nsteps; ++s) {
    const int k0 = kbeg + s * 64;
    const short* atile = Ap + (size_t)(k0 >> 6) * 512 * 64;
    s16x8 af[8];
    #pragma unroll
    for (int kk = 0; kk < 2; ++kk)
      #pragma unroll
      for (int fm = 0; fm < 4; ++fm) {
        int row = w * 64 + fm * 16 + ln15;
        af[kk * 4 + fm] = *reinterpret_cast<const s16x8*>(
            &atile[row * 64 + (kk * 4 + hi) * 8]);
      }
    if (s + 1 < nsteps) writeB((s + 1) & 1);
    if (s + 2 < nsteps) loadB(kbeg + (s + 2) * 64);

    const short* bsrc = &Bs[s & 1][0];
    #pragma unroll
    for (int kk = 0; kk < 2; ++kk) {
      const int g = kk * 4 + hi;
      #pragma unroll
      for (int fn = 0; fn < 8; ++fn) {
        int row = fn * 16 + ln15;
        s16x8 bv = *reinterpret_cast<const s16x8*>(
            &bsrc[row * 64 + ((g ^ (row & 7)) * 8)]);
        #pragma unroll
        for (int fm = 0; fm < 4; ++fm)
          acc[fm][fn] = __builtin_amdgcn_mfma_f32_16x16x32_bf16(
              af[kk * 4 + fm], bv, acc[fm][fn], 0, 0, 0);
      }
    }
    softBarrier();
  }

  #pragma unroll
  for (int fm = 0; fm < 4; ++fm)
    #pragma unroll
    for (int fn = 0; fn < 8; ++fn)
      #pragma unroll
      for (int j = 0; j < 4; ++j) {
        int row = w * 64 + fm * 16 + hi * 4 + j;
        int col = n0 + fn * 16 + ln15;
        part[((size_t)z * 512 + row) * N + col] = acc[fm][fn][j];
      }
}

// ---------------------------------------------------------------------------
// split-K reduce for mlp1: h3 = gelu(sum part + b1), bf16, TILE-PACKED out
// ---------------------------------------------------------------------------
__global__ __launch_bounds__(256) void reduce_mlp1_k(
    const float* __restrict__ part, const float* __restrict__ bias,
    short* __restrict__ h3p, int N, int Nreal, int M, int ks)
{
  int col4 = (blockIdx.x * 256 + threadIdx.x) * 4;
  int row = blockIdx.y;
  if (col4 >= N) return;
  size_t base = (size_t)row * N + col4;
  size_t stride = (size_t)M * N;
  f32x4 s = *reinterpret_cast<const f32x4*>(part + base);
  for (int k = 1; k < ks; ++k)
    s += *reinterpret_cast<const f32x4*>(part + base + (size_t)k * stride);
  s16x4 o;
  #pragma unroll
  for (int j = 0; j < 4; ++j) {
    int c = col4 + j;
    float v = 0.f;
    if (c < Nreal) v = gelu_f(s[j] + bias[c]);
    o[j] = f2bf(v);
  }
  size_t paddr = ((size_t)(col4 >> 6) * 512 + row) * 64 + (col4 & 63);
  *reinterpret_cast<s16x4*>(&h3p[paddr]) = o;
}

// ---------------------------------------------------------------------------
// split-K reduce for mlp2: out = sum part + b2 + x1 (f32)
// ---------------------------------------------------------------------------
__global__ __launch_bounds__(256) void reduce_mlp2_k(
    const float* __restrict__ part, const float* __restrict__ bias,
    const float* __restrict__ x1, float* __restrict__ out, int N, int M, int ks)
{
  int col4 = (blockIdx.x * 256 + threadIdx.x) * 4;
  int row = blockIdx.y;
  size_t base = (size_t)row * N + col4;
  size_t stride = (size_t)M * N;
  f32x4 s = *reinterpret_cast<const f32x4*>(part + base);
  for (int k = 1; k < ks; ++k)
    s += *reinterpret_cast<const f32x4*>(part + base + (size_t)k * stride);
  f32x4 b4 = *reinterpret_cast<const f32x4*>(bias + col4);
  f32x4 r4 = *reinterpret_cast<const f32x4*>(x1 + base);
  #pragma unroll
  for (int j = 0; j < 4; ++j) s[j] += b4[j] + r4[j];
  *reinterpret_cast<f32x4*>(out + base) = s;
}

// ---------------------------------------------------------------------------
// K5: SGU gate
// ---------------------------------------------------------------------------
__global__ __launch_bounds__(256) void gate_k(
    const float* __restrict__ u, const short* __restrict__ vbf,
    const float* __restrict__ a,
    const float* __restrict__ spg_g, const float* __restrict__ spg_b,
    const float* __restrict__ spw, const float* __restrict__ spb,
    const float* __restrict__ pog, const float* __restrict__ pob,
    short* __restrict__ outn)
{
  __shared__ __align__(16) short nvb[256][72];
  __shared__ __align__(16) short spwT[64][72];
  __shared__ float s_spg[64], s_spbl[64], s_spb[64];
  __shared__ float s_pog[256], s_pob[256];
  int t = threadIdx.x, lane = t & 63, w = t >> 6;
  int ln15 = lane & 15, hi = lane >> 4;
  int b = blockIdx.x;

  if (t < 64) { s_spg[t] = spg_g[t]; s_spbl[t] = spg_b[t]; s_spb[t] = spb[t]; }
  s_pog[t] = pog[t]; s_pob[t] = pob[t];
  #pragma unroll
  for (int i = 0; i < 16; ++i) {
    int idx = i*256 + t;
    int sr = idx >> 6, tc = idx & 63;
    spwT[tc][sr] = f2bf(spw[idx]);
  }

  float vvv[64];
  {
    int c = t;
    float s = 0.f, sq = 0.f;
    #pragma unroll
    for (int si = 0; si < 64; ++si) {
      float f = bf2f(vbf[(size_t)(b*64 + si) * 256 + c]);
      vvv[si] = f; s += f; sq += f*f;
    }
    float m = s * (1.f/64.f);
    float rstd = rsqrtf(sq * (1.f/64.f) - m*m + 1e-5f);
    __syncthreads();
    #pragma unroll
    for (int si = 0; si < 64; ++si)
      nvb[c][si] = f2bf((vvv[si]-m)*rstd*s_spg[si] + s_spbl[si]);
  }
  __syncthreads();

  f32x4 yacc[4][4] = {};
  #pragma unroll
  for (int kk = 0; kk < 64; kk += 32) {
    s16x8 af[4], bfr[4];
    #pragma unroll
    for (int fm = 0; fm < 4; ++fm)
      af[fm] = *reinterpret_cast<const s16x8*>(&nvb[64*w + fm*16 + ln15][kk + hi*8]);
    #pragma unroll
    for (int fn = 0; fn < 4; ++fn)
      bfr[fn] = *reinterpret_cast<const s16x8*>(&spwT[fn*16 + ln15][kk + hi*8]);
    #pragma unroll
    for (int fm = 0; fm < 4; ++fm)
      #pragma unroll
      for (int fn = 0; fn < 4; ++fn)
        yacc[fm][fn] = __builtin_amdgcn_mfma_f32_16x16x32_bf16(
            af[fm], bfr[fn], yacc[fm][fn], 0, 0, 0);
  }
  __syncthreads();

  short (*outl)[264] = reinterpret_cast<short(*)[264]>(&nvb[0][0]);
  #pragma unroll
  for (int fm = 0; fm < 4; ++fm) {
    #pragma unroll
    for (int fn = 0; fn < 4; ++fn) {
      int crow = 64*w + fm*16 + hi*4;
      int tcol = fn*16 + ln15;
      f32x4 u4 = *reinterpret_cast<const f32x4*>(&u[(size_t)(b*64 + tcol)*256 + crow]);
      f32x4 a4 = *reinterpret_cast<const f32x4*>(&a[(size_t)(b*64 + tcol)*256 + crow]);
      #pragma unroll
      for (int j = 0; j < 4; ++j) {
        float g = gelu_f(yacc[fm][fn][j] + s_spb[tcol]);
        float o = u4[j] * (g + a4[j]);
        outl[tcol][crow + j] = f2bf(o);
      }
    }
  }
  __syncthreads();

  #pragma unroll
  for (int ri = 0; ri < 16; ++ri) {
    int trow = w*16 + ri;
    int c = lane * 4;
    s16x4 raw = *reinterpret_cast<const s16x4*>(&outl[trow][c]);
    float f0 = bf2f(raw[0]), f1 = bf2f(raw[1]), f2 = bf2f(raw[2]), f3 = bf2f(raw[3]);
    float s  = f0+f1+f2+f3;
    float sq = f0*f0+f1*f1+f2*f2+f3*f3;
    s = waveSum(s); sq = waveSum(sq);
    float m = s * (1.f/256.f);
    float rstd = rsqrtf(sq * (1.f/256.f) - m*m + 1e-5f);
    s16x4 o;
    o[0] = f2bf((f0-m)*rstd*s_pog[c+0] + s_pob[c+0]);
    o[1] = f2bf((f1-m)*rstd*s_pog[c+1] + s_pob[c+1]);
    o[2] = f2bf((f2-m)*rstd*s_pog[c+2] + s_pob[c+2]);
    o[3] = f2bf((f3-m)*rstd*s_pog[c+3] + s_pob[c+3]);
    *reinterpret_cast<s16x4*>(&outn[(size_t)(b*64 + trow)*256 + c]) = o;
  }
}

// ---------------------------------------------------------------------------
extern "C" void kernel_launch(void* const* d_in, const int* in_sizes, int n_in,
                              void* d_out, int out_size, void* d_ws, size_t ws_size,
                              hipStream_t stream)
{
  const float* x          = (const float*)d_in[0];
  const float* qkv_ln_g   = (const float*)d_in[1];
  const float* qkv_ln_b   = (const float*)d_in[2];
  const float* qkv_w      = (const float*)d_in[3];
  const float* qkv_b      = (const float*)d_in[4];
  const float* attn_pw    = (const float*)d_in[5];
  const float* attn_pb    = (const float*)d_in[6];
  const float* attn_ln_g  = (const float*)d_in[7];
  const float* attn_ln_b  = (const float*)d_in[8];
  const float* rel_bias   = (const float*)d_in[9];
  const float* scale      = (const float*)d_in[10];
  const float* pin_ln_g   = (const float*)d_in[11];
  const float* pin_ln_b   = (const float*)d_in[12];
  const float* pin_w      = (const float*)d_in[13];
  const float* pin_b      = (const float*)d_in[14];
  const float* sp_ln_g    = (const float*)d_in[15];
  const float* sp_ln_b    = (const float*)d_in[16];
  const float* sp_w       = (const float*)d_in[17];
  const float* sp_b       = (const float*)d_in[18];
  const float* pout_ln_g  = (const float*)d_in[19];
  const float* pout_ln_b  = (const float*)d_in[20];
  const float* pout_w     = (const float*)d_in[21];
  const float* pout_b     = (const float*)d_in[22];
  const float* mlp_ln_g   = (const float*)d_in[23];
  const float* mlp_ln_b   = (const float*)d_in[24];
  const float* mlp_w1     = (const float*)d_in[25];
  const float* mlp_b1     = (const float*)d_in[26];
  const float* mlp_w2     = (const float*)d_in[27];
  const float* mlp_b2     = (const float*)d_in[28];

  char* ws = (char*)d_ws;
  short* lnp   = (short*)(ws + 0);           // 8.39 MB (dead after pin gemm)
  float* x1b   = (float*)(ws + 0);           // 16.78 MB (written at pout)
  float* ab    = (float*)(ws + 16777216);    // 33.55 MB f32
  float* ub    = (float*)(ws + 50331648);    // 33.55 MB f32
  short* wTg   = (short*)(ws + 83886080);    // 393 KB (pre-pin region)
  short* pwTg  = (short*)(ws + 84279296);    // 262 KB
  short* vbfb  = (short*)(ws + 83886080);    // 16.78 MB bf16 (after fused)
  short* outnb = (short*)(ws + 100663296);   // 16.78 MB bf16
  short* lnxp  = (short*)(ws + 150994944);   // 8.39 MB (tile-packed)
  short* h3p   = (short*)(ws + 159383552);   // 9.31 MB (tile-packed)
  float* partb = (float*)(ws + 16777216);    // split-K partials (<=74.5 MB)

  // weight transpose (once) -> wTg, pwTg
  prep_w_k<<<160, 256, 0, stream>>>(qkv_w, attn_pw, wTg, pwTg);
  // fused: LN + qkv + attention + proj + ln256  ->  lnp, ab
  fused_attn_k<<<512, 256, 0, stream>>>(
      x, qkv_ln_g, qkv_ln_b, pin_ln_g, pin_ln_b, wTg, qkv_b,
      pwTg, attn_pb, attn_ln_g, attn_ln_b, rel_bias, scale, lnp, ab);
  // pin: [32768,128]@[128,512]+b, gelu, split u (f32) / v (bf16)
  gemm_k<128,128,2,2,2><<<dim3(4,256), 256, 0, stream>>>(
      lnp, pin_w, pin_b, nullptr, ub, vbfb, 32768, 512, 128, 512, 128);
  // SGU gate + fused pout_ln -> outn bf16
  gate_k<<<512, 256, 0, stream>>>(ub, vbfb, ab, sp_ln_g, sp_ln_b, sp_w, sp_b,
                                  pout_ln_g, pout_ln_b, outnb);
  // pout: [32768,256]@[256,128]+b + x residual -> x1 f32
  gemm_k<128,128,2,2,3><<<dim3(1,256), 256, 0, stream>>>(
      outnb, pout_w, pout_b, x, x1b, nullptr, 32768, 128, 256, 128, 256);
  // LN over 8192 -> lnx (tile-packed)
  ln8192_k<<<512, 256, 0, stream>>>(x1b, mlp_ln_g, mlp_ln_b, lnxp);

  // mlp1: [512,8192] @ [8192,9011] (N padded 9088), split-K 3, 213 blocks
  gemm_splitk9<<<213, 512, 0, stream>>>(
      lnxp, mlp_w1, partb, /*N=*/9088, /*K=*/8192, /*Kreal=*/8192,
      /*ldb=*/9011, /*kchunk=*/2752, /*ntiles=*/71);
  reduce_mlp1_k<<<dim3(9, 512), 256, 0, stream>>>(partb, mlp_b1, h3p, 9088, 9011, 512, 3);

  // mlp2: [512,9088] @ [9011,8192], split-K 4, 256 blocks
  gemm_splitk9<<<256, 512, 0, stream>>>(
      h3p, mlp_w2, partb, /*N=*/8192, /*K=*/9088, /*Kreal=*/9011,
      /*ldb=*/8192, /*kchunk=*/2304, /*ntiles=*/64);
  reduce_mlp2_k<<<dim3(8, 512), 256, 0, stream>>>(partb, mlp_b2, x1b, (float*)d_out, 8192, 512, 4);
}